// Round 13
// baseline (886.803 us; speedup 1.0000x reference)
//
#include <hip/hip_runtime.h>

namespace {

constexpr int Bb = 8;
constexpr int Nn = 4097;
constexpr int Cc = 768;
constexpr int Hh = 12;
constexpr int HD = 64;
constexpr int Aa = 49;
constexpr int LDQ = 3 * Cc;        // 2304 (qkv row stride)
constexpr int NCH = 16;            // j-chunks for agent attention
constexpr int CHUNK = (Nn + NCH - 1) / NCH;  // 257
constexpr float SCALE = 0.125f;    // hd^-0.5
constexpr int KP = 1536;           // packed plane row length (hi 768 | lo 768)

typedef short s16x8 __attribute__((ext_vector_type(8)));
typedef float f32x4 __attribute__((ext_vector_type(4)));

struct HL { short h, l; };

// Split fp32 into hi (truncated bf16, exact bits) + lo (RNE bf16 of residual).
__device__ inline HL splitbf(float v) {
  unsigned u = __float_as_uint(v);
  HL r;
  r.h = (short)(u >> 16);
  float hf = __uint_as_float(u & 0xffff0000u);
  float lf = v - hf;
  unsigned ul = __float_as_uint(lf);
  r.l = (short)((ul + 0x7fffu + ((ul >> 16) & 1u)) >> 16);
  return r;
}

__device__ inline unsigned short bf16rne(float v) {
  unsigned u = __float_as_uint(v);
  return (unsigned short)((u + 0x7fffu + ((u >> 16) & 1u)) >> 16);
}
__device__ inline float bf2f(unsigned short s) {
  return __uint_as_float((unsigned)s << 16);
}

// async global->LDS, 16B per lane (linear dest)
__device__ inline void gload16(const short* g, void* l) {
  __builtin_amdgcn_global_load_lds(
      (const __attribute__((address_space(1))) void*)g,
      (__attribute__((address_space(3))) void*)l, 16, 0, 0);
}

// Packed layout (R11): per row, 24 windows of 32 elems (4 chunks of 8);
// physical chunk = logical chunk ^ ((row>>1)&3). hi [0,768), lo [768,1536).
// BK=32 slices are self-contained; frag reads see <=2-way conflicts (free).

// ---------------------------------------------------------------------------
// Pack activations: src[M][768] fp32 -> dst[M][1536] bf16 = [hi | lo].
// ---------------------------------------------------------------------------
__global__ __launch_bounds__(256) void pack_act(
    const float* __restrict__ src, short* __restrict__ dst, int M) {
  int idx = blockIdx.x * 256 + threadIdx.x;
  if (idx >= M * 96) return;
  int m = idx / 96, kc = idx - m * 96;
  const float* s = src + (size_t)m * 768 + kc * 8;
  float4 v0 = *(const float4*)s;
  float4 v1 = *(const float4*)(s + 4);
  s16x8 hv, lv;
  HL r;
  r = splitbf(v0.x); hv[0] = r.h; lv[0] = r.l;
  r = splitbf(v0.y); hv[1] = r.h; lv[1] = r.l;
  r = splitbf(v0.z); hv[2] = r.h; lv[2] = r.l;
  r = splitbf(v0.w); hv[3] = r.h; lv[3] = r.l;
  r = splitbf(v1.x); hv[4] = r.h; lv[4] = r.l;
  r = splitbf(v1.y); hv[5] = r.h; lv[5] = r.l;
  r = splitbf(v1.z); hv[6] = r.h; lv[6] = r.l;
  r = splitbf(v1.w); hv[7] = r.h; lv[7] = r.l;
  int win = (kc >> 2) * 32;
  int jj = ((kc & 3) ^ ((m >> 1) & 3)) * 8;
  short* d = dst + (size_t)m * KP;
  *(s16x8*)&d[win + jj] = hv;
  *(s16x8*)&d[768 + win + jj] = lv;
}

// ---------------------------------------------------------------------------
// Pack weights: W[768][N] fp32 -> Wpk[N][1536] bf16, swizzle keyed (n>>1)&3.
// ---------------------------------------------------------------------------
__global__ __launch_bounds__(256) void pack_w(
    const float* __restrict__ W, short* __restrict__ Wpk, int N) {
  int idx = blockIdx.x * 256 + threadIdx.x;
  if (idx >= 96 * N) return;
  int kc = idx / N, n = idx - kc * N;
  s16x8 hv, lv;
#pragma unroll
  for (int i = 0; i < 8; ++i) {
    HL r = splitbf(W[(size_t)(kc * 8 + i) * N + n]);
    hv[i] = r.h; lv[i] = r.l;
  }
  int win = (kc >> 2) * 32;
  int jj = ((kc & 3) ^ ((n >> 1) & 3)) * 8;
  short* d = Wpk + (size_t)n * KP;
  *(s16x8*)&d[win + jj] = hv;
  *(s16x8*)&d[768 + win + jj] = lv;
}

// ---------------------------------------------------------------------------
// C[M x N] = A @ B (+bias) on packed planes. BK=32 DOUBLE-BUFFERED with
// COUNTED vmcnt + RAW s_barrier (T4): per iter, stage(next buf) is issued
// first (8 global_load_lds/thread), then `s_waitcnt vmcnt(8)` waits ONLY the
// previous tile's loads -> the new 8 stay in flight across the barrier and
// land during this iter's 48 MFMAs. No compiler __syncthreads (whose
// vmcnt(0) drain serialized R11). 24 kt iterations, uniform epilogue.
// ---------------------------------------------------------------------------
__global__ __launch_bounds__(256) void gemm_pk2(
    const short* __restrict__ Apk, const short* __restrict__ Bpk,
    float* __restrict__ Cm, const float* __restrict__ bias,
    int Mr, int ldc, int nch, int nwg) {
  __shared__ __align__(16) short AsH[2][128 * 32], AsL[2][128 * 32];
  __shared__ __align__(16) short BsH[2][128 * 32], BsL[2][128 * 32];
  const int t = threadIdx.x;
  const int lane = t & 63;
  const int w = t >> 6;
  const int wr = w >> 1, wc = w & 1;
  const int l15 = lane & 15, l4 = lane >> 4;

  const int j = blockIdx.x;
  const int q = nwg >> 3, r = nwg & 7;
  const int xcd = j & 7, pos = j >> 3;
  const int logical =
      (xcd < r ? xcd * (q + 1) : r * (q + 1) + (xcd - r) * q) + pos;
  const int mt = logical / nch, nc = logical - mt * nch;
  const int m0 = mt * 128, n0 = nc * 128;

  f32x4 acc[4][4];
#pragma unroll
  for (int mi = 0; mi < 4; ++mi)
#pragma unroll
    for (int ni = 0; ni < 4; ++ni) acc[mi][ni] = (f32x4){0.f, 0.f, 0.f, 0.f};

  auto stage = [&](int buf, int kt) {
#pragma unroll
    for (int i = 0; i < 2; ++i) {
      const int o = (i * 256 + t) * 16;   // byte offset in 8KB plane
      const int row = o >> 6;             // 64B per row
      const int ce = (o & 63) >> 1;       // element col (physical)
      gload16(Apk + (size_t)(m0 + row) * KP + kt * 32 + ce,
              (char*)AsH[buf] + o);
      gload16(Apk + (size_t)(m0 + row) * KP + 768 + kt * 32 + ce,
              (char*)AsL[buf] + o);
      gload16(Bpk + (size_t)(n0 + row) * KP + kt * 32 + ce,
              (char*)BsH[buf] + o);
      gload16(Bpk + (size_t)(n0 + row) * KP + 768 + kt * 32 + ce,
              (char*)BsL[buf] + o);
    }
  };

  stage(0, 0);                     // prologue: 8 loads in flight

  for (int kt = 0; kt < 24; ++kt) {
    const int cur = kt & 1;
    // issue next tile's 8 loads (wraps to kt=0 on last iter: dead buffer,
    // keeps per-thread vmcnt math uniform at literal 8)
    stage(cur ^ 1, (kt + 1 < 24) ? kt + 1 : 0);
    // wait ONLY the previous 8 (buf[cur]); the new 8 remain outstanding
    asm volatile("s_waitcnt vmcnt(8)" ::: "memory");
    __builtin_amdgcn_s_barrier();              // buf[cur] ready for all waves
    __builtin_amdgcn_sched_barrier(0);         // pin ds_reads after barrier

    s16x8 ah[4], al[4], bh[4], bl[4];
    const int key = ((l15 >> 1) & 3);
#pragma unroll
    for (int mi = 0; mi < 4; ++mi) {
      int rr = wr * 64 + mi * 16 + l15;
      int off = rr * 32 + ((l4 ^ key) << 3);
      ah[mi] = *(const s16x8*)&AsH[cur][off];
      al[mi] = *(const s16x8*)&AsL[cur][off];
    }
#pragma unroll
    for (int ni = 0; ni < 4; ++ni) {
      int rr = wc * 64 + ni * 16 + l15;
      int off = rr * 32 + ((l4 ^ key) << 3);
      bh[ni] = *(const s16x8*)&BsH[cur][off];
      bl[ni] = *(const s16x8*)&BsL[cur][off];
    }
#pragma unroll
    for (int mi = 0; mi < 4; ++mi)
#pragma unroll
      for (int ni = 0; ni < 4; ++ni) {
        acc[mi][ni] = __builtin_amdgcn_mfma_f32_16x16x32_bf16(
            ah[mi], bh[ni], acc[mi][ni], 0, 0, 0);
        acc[mi][ni] = __builtin_amdgcn_mfma_f32_16x16x32_bf16(
            ah[mi], bl[ni], acc[mi][ni], 0, 0, 0);
        acc[mi][ni] = __builtin_amdgcn_mfma_f32_16x16x32_bf16(
            al[mi], bh[ni], acc[mi][ni], 0, 0, 0);
      }
    // done reading buf[cur] (MFMAs consumed the data) -> safe to overwrite
    // it at iter kt+2; raw barrier, no vmcnt drain.
    __builtin_amdgcn_s_barrier();
  }

#pragma unroll
  for (int mi = 0; mi < 4; ++mi) {
#pragma unroll
    for (int jr = 0; jr < 4; ++jr) {
      int gr = m0 + wr * 64 + mi * 16 + l4 * 4 + jr;
      if (gr < Mr) {
#pragma unroll
        for (int ni = 0; ni < 4; ++ni) {
          int gc = n0 + wc * 64 + ni * 16 + l15;
          float v = acc[mi][ni][jr];
          if (bias) v += bias[gc];
          Cm[(size_t)gr * ldc + gc] = v;
        }
      }
    }
  }
}

// ---------------------------------------------------------------------------
// Adaptive-pool agents: at[bg,a,c] = mean over q rows [s,e) of q[bg,l,c].
// ---------------------------------------------------------------------------
__global__ __launch_bounds__(192) void pool_agents(
    const float* __restrict__ qkv, float* __restrict__ at) {
  const int ba = blockIdx.x;
  const int bg = ba / Aa, a = ba % Aa;
  const int s = (a * 4096) / 49;
  const int e = ((a + 1) * 4096 + 48) / 49;
  const float w = 1.0f / (float)(e - s);
  const int c4 = threadIdx.x * 4;
  f32x4 sum = (f32x4){0.f, 0.f, 0.f, 0.f};
#pragma unroll 4
  for (int l = s; l < e; ++l) {
    const float4 v = *(const float4*)&qkv[(size_t)(bg * Nn + l) * LDQ + c4];
    sum[0] += v.x; sum[1] += v.y; sum[2] += v.z; sum[3] += v.w;
  }
  float4 o;
  o.x = sum[0] * w; o.y = sum[1] * w; o.z = sum[2] * w; o.w = sum[3] * w;
  *(float4*)&at[(size_t)(bg * Aa + a) * Cc + c4] = o;
}

// ---------------------------------------------------------------------------
// Agent attention via MFMA split-bf16. 48KB LDS, P aliases K planes.
// ---------------------------------------------------------------------------
__global__ __launch_bounds__(256) void agent_attn_mfma(
    const float* __restrict__ qkv, const float* __restrict__ at,
    float* __restrict__ paccv, float* __restrict__ paccs) {
  const int chunk = blockIdx.x, h = blockIdx.y, bg = blockIdx.z;
  __shared__ __align__(16) short AhH[4096], AhL[4096];  // ah [a][d]
  __shared__ __align__(16) short KH[4096], KL[4096];    // K [j][d]; P aliases
  __shared__ __align__(16) short VtH[4096], VtL[4096];  // V^T [c][j]
  const int t = threadIdx.x;
  const int w = t >> 6, lane = t & 63, l15 = lane & 15, l4 = lane >> 4;

  for (int idx = t; idx < 512; idx += 256) {
    int a = idx >> 3, c8 = idx & 7;
    float vals[8];
    if (a < Aa) {
      const float* src = &at[(size_t)(bg * Aa + a) * Cc + h * HD + c8 * 8];
      *(float4*)&vals[0] = *(const float4*)src;
      *(float4*)&vals[4] = *(const float4*)(src + 4);
    } else {
#pragma unroll
      for (int i = 0; i < 8; ++i) vals[i] = 0.f;
    }
    s16x8 hv, lv;
#pragma unroll
    for (int i = 0; i < 8; ++i) {
      HL r = splitbf(vals[i]);
      hv[i] = r.h; lv[i] = r.l;
    }
    int pos = a * 64 + ((c8 ^ (a & 7)) << 3);
    *(s16x8*)&AhH[pos] = hv;
    *(s16x8*)&AhL[pos] = lv;
  }

  f32x4 acc[4];
#pragma unroll
  for (int ni = 0; ni < 4; ++ni) acc[ni] = (f32x4){0.f, 0.f, 0.f, 0.f};
  float rs[4] = {0.f, 0.f, 0.f, 0.f};

  const int jstart = chunk * CHUNK;
  const int jend = min(jstart + CHUNK, Nn);
  const int srow = t >> 2, sc0 = (t & 3) * 16;

  for (int j0 = jstart; j0 < jend; j0 += 64) {
    __syncthreads();
    {
      int jg = j0 + srow;
      float kv[16], vv[16];
      if (jg < jend) {
        const float* p = &qkv[(size_t)(bg * Nn + jg) * LDQ + Cc + h * HD + sc0];
#pragma unroll
        for (int r = 0; r < 4; ++r) {
          *(float4*)&kv[r * 4] = *(const float4*)(p + r * 4);
          *(float4*)&vv[r * 4] = *(const float4*)(p + Cc + r * 4);
        }
      } else {
#pragma unroll
        for (int i = 0; i < 16; ++i) { kv[i] = 0.f; vv[i] = 0.f; }
      }
#pragma unroll
      for (int r = 0; r < 2; ++r) {
        s16x8 hv, lv;
#pragma unroll
        for (int i = 0; i < 8; ++i) {
          HL s = splitbf(kv[r * 8 + i]);
          hv[i] = s.h; lv[i] = s.l;
        }
        int ch = (sc0 >> 3) + r;
        int pos = srow * 64 + ((ch ^ (srow & 7)) << 3);
        *(s16x8*)&KH[pos] = hv;
        *(s16x8*)&KL[pos] = lv;
      }
#pragma unroll
      for (int i = 0; i < 16; ++i) {
        HL s = splitbf(vv[i]);
        int c = sc0 + i;
        int pos = c * 64 + ((((srow >> 3) ^ (c & 7)) << 3)) + (srow & 7);
        VtH[pos] = s.h;
        VtL[pos] = s.l;
      }
    }
    __syncthreads();

    f32x4 s[4];
#pragma unroll
    for (int ni = 0; ni < 4; ++ni) s[ni] = (f32x4){0.f, 0.f, 0.f, 0.f};
#pragma unroll
    for (int ks = 0; ks < 2; ++ks) {
      int sw = (((ks << 2) + l4) ^ (l15 & 7)) << 3;
      s16x8 ahh = *(const s16x8*)&AhH[(w * 16 + l15) * 64 + sw];
      s16x8 ahl = *(const s16x8*)&AhL[(w * 16 + l15) * 64 + sw];
#pragma unroll
      for (int ni = 0; ni < 4; ++ni) {
        s16x8 kh = *(const s16x8*)&KH[(ni * 16 + l15) * 64 + sw];
        s16x8 kl = *(const s16x8*)&KL[(ni * 16 + l15) * 64 + sw];
        s[ni] = __builtin_amdgcn_mfma_f32_16x16x32_bf16(ahh, kh, s[ni], 0, 0, 0);
        s[ni] = __builtin_amdgcn_mfma_f32_16x16x32_bf16(ahh, kl, s[ni], 0, 0, 0);
        s[ni] = __builtin_amdgcn_mfma_f32_16x16x32_bf16(ahl, kh, s[ni], 0, 0, 0);
      }
    }
    __syncthreads();

#pragma unroll
    for (int ni = 0; ni < 4; ++ni) {
#pragma unroll
      for (int reg = 0; reg < 4; ++reg) {
        int jj = l15 + 16 * ni;
        float pv = (j0 + jj < jend) ? expf(s[ni][reg] * SCALE) : 0.f;
        rs[reg] += pv;
        HL r = splitbf(pv);
        int a = w * 16 + l4 * 4 + reg;
        int pos = a * 64 + ((((jj >> 3) ^ (a & 7)) << 3)) + (jj & 7);
        KH[pos] = r.h;
        KL[pos] = r.l;
      }
    }
    __syncthreads();

#pragma unroll
    for (int ks = 0; ks < 2; ++ks) {
      int sw = (((ks << 2) + l4) ^ (l15 & 7)) << 3;
      s16x8 ph = *(const s16x8*)&KH[(w * 16 + l15) * 64 + sw];
      s16x8 pl = *(const s16x8*)&KL[(w * 16 + l15) * 64 + sw];
#pragma unroll
      for (int ni = 0; ni < 4; ++ni) {
        s16x8 vh = *(const s16x8*)&VtH[(ni * 16 + l15) * 64 + sw];
        s16x8 vl = *(const s16x8*)&VtL[(ni * 16 + l15) * 64 + sw];
        acc[ni] = __builtin_amdgcn_mfma_f32_16x16x32_bf16(ph, vh, acc[ni], 0, 0, 0);
        acc[ni] = __builtin_amdgcn_mfma_f32_16x16x32_bf16(ph, vl, acc[ni], 0, 0, 0);
        acc[ni] = __builtin_amdgcn_mfma_f32_16x16x32_bf16(pl, vh, acc[ni], 0, 0, 0);
      }
    }
  }

#pragma unroll
  for (int reg = 0; reg < 4; ++reg) {
    rs[reg] += __shfl_xor(rs[reg], 1);
    rs[reg] += __shfl_xor(rs[reg], 2);
    rs[reg] += __shfl_xor(rs[reg], 4);
    rs[reg] += __shfl_xor(rs[reg], 8);
  }
  const int basev = ((bg * Hh + h) * NCH + chunk) * (Aa * 64);
#pragma unroll
  for (int reg = 0; reg < 4; ++reg) {
    int a = w * 16 + l4 * 4 + reg;
    if (a < Aa) {
#pragma unroll
      for (int ni = 0; ni < 4; ++ni)
        paccv[basev + a * 64 + l15 + 16 * ni] = acc[ni][reg];
      if (l15 == 0)
        paccs[((bg * Hh + h) * NCH + chunk) * Aa + a] = rs[reg];
    }
  }
}

// ---------------------------------------------------------------------------
// Merge chunk partials -> agent_v[bgh,a,c]
// ---------------------------------------------------------------------------
__global__ __launch_bounds__(256) void merge_agent(
    const float* __restrict__ paccv, const float* __restrict__ paccs,
    float* __restrict__ av) {
  const int bh = blockIdx.x;
  const int t = threadIdx.x;
  for (int idx = t; idx < Aa * HD; idx += 256) {
    int a = idx >> 6;
    float vs = 0.f, ss = 0.f;
#pragma unroll
    for (int ch = 0; ch < NCH; ++ch) {
      vs += paccv[(size_t)((bh * NCH + ch)) * (Aa * 64) + idx];
      ss += paccs[(bh * NCH + ch) * Aa + a];
    }
    av[(size_t)bh * (Aa * HD) + idx] = vs / ss;
  }
}

// ---------------------------------------------------------------------------
// FUSED q attention + dwc + split-pack. Vectorized epilogue: O -> LDS,
// re-gather into whole 8-channel chunks -> 16B coalesced stores (R11 packed
// layout: win=(kcg>>2)*32, jj=((kcg&3)^((mrow>>1)&3))*8).
// ---------------------------------------------------------------------------
__global__ __launch_bounds__(256) void q_attn_dwc(
    const float* __restrict__ qkv, const float* __restrict__ at,
    const float* __restrict__ av, const float* __restrict__ dwcw,
    const float* __restrict__ dwcb, short* __restrict__ Opk) {
  const int i0 = blockIdx.x * 64, h = blockIdx.y, bg = blockIdx.z;
  __shared__ __align__(16) short SMEM[24576];   // 48KB
  short* AhH = SMEM;             // [a][d] ; olds aliases after PV
  short* AhL = SMEM + 4096;
  short* AvH = SMEM + 8192;      // av^T [c][a]
  short* AvL = SMEM + 12288;
  short* QH  = SMEM + 16384;     // q [row][d]; P alias; v-stage alias
  short* QL  = SMEM + 20480;
  const int t = threadIdx.x;
  const int w = t >> 6, lane = t & 63, l15 = lane & 15, l4 = lane >> 4;

  for (int idx = t; idx < 512; idx += 256) {
    int a = idx >> 3, c8 = idx & 7;
    float vah[8], vav[8];
    if (a < Aa) {
      const float* s1 = &at[(size_t)(bg * Aa + a) * Cc + h * HD + c8 * 8];
      const float* s2 = &av[(size_t)(bg * Hh + h) * (Aa * HD) + a * HD + c8 * 8];
      *(float4*)&vah[0] = *(const float4*)s1;
      *(float4*)&vah[4] = *(const float4*)(s1 + 4);
      *(float4*)&vav[0] = *(const float4*)s2;
      *(float4*)&vav[4] = *(const float4*)(s2 + 4);
    } else {
#pragma unroll
      for (int i = 0; i < 8; ++i) { vah[i] = 0.f; vav[i] = 0.f; }
    }
    s16x8 hv, lv;
#pragma unroll
    for (int i = 0; i < 8; ++i) {
      HL r = splitbf(vah[i]);
      hv[i] = r.h; lv[i] = r.l;
    }
    int pos = a * 64 + ((c8 ^ (a & 7)) << 3);
    *(s16x8*)&AhH[pos] = hv;
    *(s16x8*)&AhL[pos] = lv;
#pragma unroll
    for (int i = 0; i < 8; ++i) {
      HL r = splitbf(vav[i]);
      int c = c8 * 8 + i;
      int pos2 = c * 64 + ((((a >> 3) ^ (c & 7)) << 3)) + (a & 7);
      AvH[pos2] = r.h;
      AvL[pos2] = r.l;
    }
  }
  {
    int row = t >> 2, c0 = (t & 3) * 16;
    int ig = i0 + row;
    float qv[16];
    if (ig < Nn) {
      const float* p = &qkv[(size_t)(bg * Nn + ig) * LDQ + h * HD + c0];
#pragma unroll
      for (int r = 0; r < 4; ++r) *(float4*)&qv[r * 4] = *(const float4*)(p + r * 4);
    } else {
#pragma unroll
      for (int i = 0; i < 16; ++i) qv[i] = 0.f;
    }
#pragma unroll
    for (int r = 0; r < 2; ++r) {
      s16x8 hv, lv;
#pragma unroll
      for (int i = 0; i < 8; ++i) {
        HL s = splitbf(qv[r * 8 + i]);
        hv[i] = s.h; lv[i] = s.l;
      }
      int ch = (c0 >> 3) + r;
      int pos = row * 64 + ((ch ^ (row & 7)) << 3);
      *(s16x8*)&QH[pos] = hv;
      *(s16x8*)&QL[pos] = lv;
    }
  }
  __syncthreads();

  // ---- S = q @ ah^T ----
  f32x4 s[4];
#pragma unroll
  for (int ni = 0; ni < 4; ++ni) s[ni] = (f32x4){0.f, 0.f, 0.f, 0.f};
#pragma unroll
  for (int ks = 0; ks < 2; ++ks) {
    int sw = (((ks << 2) + l4) ^ (l15 & 7)) << 3;
    s16x8 qh = *(const s16x8*)&QH[(w * 16 + l15) * 64 + sw];
    s16x8 ql = *(const s16x8*)&QL[(w * 16 + l15) * 64 + sw];
#pragma unroll
    for (int ni = 0; ni < 4; ++ni) {
      s16x8 bh = *(const s16x8*)&AhH[(ni * 16 + l15) * 64 + sw];
      s16x8 bl = *(const s16x8*)&AhL[(ni * 16 + l15) * 64 + sw];
      s[ni] = __builtin_amdgcn_mfma_f32_16x16x32_bf16(qh, bh, s[ni], 0, 0, 0);
      s[ni] = __builtin_amdgcn_mfma_f32_16x16x32_bf16(qh, bl, s[ni], 0, 0, 0);
      s[ni] = __builtin_amdgcn_mfma_f32_16x16x32_bf16(ql, bh, s[ni], 0, 0, 0);
    }
  }
  __syncthreads();

  // ---- softmax over agents + transpose-write P into Q planes ----
  float rsum[4] = {0.f, 0.f, 0.f, 0.f};
#pragma unroll
  for (int ni = 0; ni < 4; ++ni) {
#pragma unroll
    for (int reg = 0; reg < 4; ++reg) {
      int a = l15 + 16 * ni;
      float pv = (a < Aa) ? expf(s[ni][reg] * SCALE) : 0.f;
      s[ni][reg] = pv;
      rsum[reg] += pv;
    }
  }
#pragma unroll
  for (int reg = 0; reg < 4; ++reg) {
    rsum[reg] += __shfl_xor(rsum[reg], 1);
    rsum[reg] += __shfl_xor(rsum[reg], 2);
    rsum[reg] += __shfl_xor(rsum[reg], 4);
    rsum[reg] += __shfl_xor(rsum[reg], 8);
    rsum[reg] = 1.0f / rsum[reg];
  }
#pragma unroll
  for (int ni = 0; ni < 4; ++ni) {
#pragma unroll
    for (int reg = 0; reg < 4; ++reg) {
      HL r = splitbf(s[ni][reg] * rsum[reg]);
      int row = w * 16 + l4 * 4 + reg;
      int a = l15 + 16 * ni;
      int pos = row * 64 + ((((a >> 3) ^ (row & 7)) << 3)) + (a & 7);
      QH[pos] = r.h;
      QL[pos] = r.l;
    }
  }
  __syncthreads();

  // ---- O = P @ agent_v ----
  f32x4 o[4];
#pragma unroll
  for (int ni = 0; ni < 4; ++ni) o[ni] = (f32x4){0.f, 0.f, 0.f, 0.f};
#pragma unroll
  for (int ks = 0; ks < 2; ++ks) {
    int sw = (((ks << 2) + l4) ^ (l15 & 7)) << 3;
    s16x8 ph = *(const s16x8*)&QH[(w * 16 + l15) * 64 + sw];
    s16x8 pl = *(const s16x8*)&QL[(w * 16 + l15) * 64 + sw];
#pragma unroll
    for (int ni = 0; ni < 4; ++ni) {
      s16x8 vh = *(const s16x8*)&AvH[(ni * 16 + l15) * 64 + sw];
      s16x8 vl = *(const s16x8*)&AvL[(ni * 16 + l15) * 64 + sw];
      o[ni] = __builtin_amdgcn_mfma_f32_16x16x32_bf16(ph, vh, o[ni], 0, 0, 0);
      o[ni] = __builtin_amdgcn_mfma_f32_16x16x32_bf16(ph, vl, o[ni], 0, 0, 0);
      o[ni] = __builtin_amdgcn_mfma_f32_16x16x32_bf16(pl, vh, o[ni], 0, 0, 0);
    }
  }
  __syncthreads();  // all LDS dead -> olds / vlds may overwrite

  // ---- write O to LDS (stride 68) + stage v tile (bf16) ----
  float* olds = (float*)SMEM;                        // 64*68*4 = 17408B
  unsigned short* vlds = (unsigned short*)QH;        // 66*72*2 = 9504B
#pragma unroll
  for (int reg = 0; reg < 4; ++reg) {
    int row = w * 16 + l4 * 4 + reg;
#pragma unroll
    for (int ni = 0; ni < 4; ++ni)
      olds[row * 68 + l15 + 16 * ni] = o[ni][reg];
  }
  constexpr int VLD = 72;
  for (int idx = t; idx < 66 * 16; idx += 256) {
    int row = idx >> 4, cs = (idx & 15) << 2;
    int gr = i0 - 1 + row;
    float4 v = make_float4(0.f, 0.f, 0.f, 0.f);
    if (gr >= 0 && gr < 4096)
      v = *(const float4*)&qkv[((size_t)bg * Nn + gr) * LDQ + 2 * Cc + h * HD + cs];
    unsigned short* d = &vlds[row * VLD + cs];
    d[0] = bf16rne(v.x); d[1] = bf16rne(v.y);
    d[2] = bf16rne(v.z); d[3] = bf16rne(v.w);
  }
  __syncthreads();

  // ---- re-gather: (local row, 8-ch chunk) -> 16B stores, R11 layout ----
#pragma unroll
  for (int it = 0; it < 2; ++it) {
    int widx = t + it * 256;            // 0..511
    int ml = widx >> 3, kc = widx & 7;
    int ig = i0 + ml;
    if (ig >= Nn) continue;
    float vals[8];
    *(float4*)&vals[0] = *(const float4*)&olds[ml * 68 + kc * 8];
    *(float4*)&vals[4] = *(const float4*)&olds[ml * 68 + kc * 8 + 4];
    if (ig < Nn - 1) {
      const int rl = ml + 1;
      const unsigned short* vr = &vlds[rl * VLD + kc * 8];
#pragma unroll
      for (int cI = 0; cI < 8; ++cI) {
        int cg = h * HD + kc * 8 + cI;
        float vm = bf2f(vr[cI - VLD]);
        float v0 = bf2f(vr[cI]);
        float vp = bf2f(vr[cI + VLD]);
        vals[cI] += dwcw[cg * 3] * vm + dwcw[cg * 3 + 1] * v0 +
                    dwcw[cg * 3 + 2] * vp + dwcb[cg];
      }
    }
    s16x8 hv, lv;
#pragma unroll
    for (int cI = 0; cI < 8; ++cI) {
      HL r = splitbf(vals[cI]);
      hv[cI] = r.h; lv[cI] = r.l;
    }
    const int mrow = bg * Nn + ig;
    const int kcg = h * 8 + kc;
    const int win = (kcg >> 2) * 32;
    const int jj = ((kcg & 3) ^ ((mrow >> 1) & 3)) * 8;
    *(s16x8*)&Opk[(size_t)mrow * KP + win + jj] = hv;
    *(s16x8*)&Opk[(size_t)mrow * KP + 768 + win + jj] = lv;
  }
}

}  // namespace

extern "C" void kernel_launch(void* const* d_in, const int* in_sizes, int n_in,
                              void* d_out, int out_size, void* d_ws,
                              size_t ws_size, hipStream_t stream) {
  const float* x = (const float*)d_in[0];
  const float* Wqkv = (const float*)d_in[1];
  const float* Wproj = (const float*)d_in[2];
  const float* bproj = (const float*)d_in[3];
  const float* dwcw = (const float*)d_in[4];
  const float* dwcb = (const float*)d_in[5];
  float* out = (float*)d_out;

  // --- fixed workspace: packed weight planes ---
  char* p = (char*)d_ws;
  short* WQpk = (short*)p; p += (size_t)LDQ * KP * 2;   // 7,077,888 B
  short* WPpk = (short*)p; p += (size_t)Cc * KP * 2;    // 2,359,296 B
  const size_t fixedBytes = (size_t)p - (size_t)d_ws;

  auto bytesFor = [&](int G) -> size_t {
    size_t Mg = (size_t)G * Nn;
    size_t Mpad = ((Mg + 127) / 128) * 128;
    size_t fl = Mg * LDQ +
                (size_t)G * (Aa * Cc + Hh * NCH * Aa * 64 + Hh * NCH * Aa +
                             Hh * Aa * HD);
    return fixedBytes + fl * 4 + Mpad * KP * 2;            // + Apk/Opk
  };
  int G = 1;
  for (int g = Bb; g >= 1; --g) {
    if (bytesFor(g) <= ws_size) { G = g; break; }
  }

  const size_t MgMax = (size_t)G * Nn;
  float* qkv = (float*)p;
  float* at = qkv + MgMax * LDQ;
  float* paccv = at + (size_t)G * Aa * Cc;
  float* paccs = paccv + (size_t)G * Hh * NCH * Aa * 64;
  float* av = paccs + (size_t)G * Hh * NCH * Aa;
  short* Apk = (short*)(av + (size_t)G * Hh * Aa * HD);   // aliased as Opk

  dim3 blk(256);
  // 0) pack weights (once per launch; deterministic)
  pack_w<<<dim3((96 * LDQ + 255) / 256), blk, 0, stream>>>(Wqkv, WQpk, LDQ);
  pack_w<<<dim3((96 * Cc + 255) / 256), blk, 0, stream>>>(Wproj, WPpk, Cc);

  for (int b0 = 0; b0 < Bb; b0 += G) {
    const int Gi = (b0 + G <= Bb) ? G : (Bb - b0);
    const int Mg = Gi * Nn;
    const int Mtiles = (Mg + 127) / 128;
    const float* xg = x + (size_t)b0 * Nn * Cc;
    float* outg = out + (size_t)b0 * Nn * Cc;

    // 1) pack x -> Apk, then qkv = x @ Wqkv (counted-vmcnt MFMA GEMM)
    pack_act<<<dim3((Mg * 96 + 255) / 256), blk, 0, stream>>>(xg, Apk, Mg);
    {
      const int nch = LDQ / 128;            // 18
      const int nwg = Mtiles * nch;
      gemm_pk2<<<dim3(nwg), blk, 0, stream>>>(Apk, WQpk, qkv, nullptr, Mg,
                                              LDQ, nch, nwg);
    }
    // 2) agent tokens (adaptive pool of q)
    pool_agents<<<dim3(Gi * Aa), dim3(192), 0, stream>>>(qkv, at);
    // 3) agent attention partials (MFMA) + merge -> agent_v
    agent_attn_mfma<<<dim3(NCH, Hh, Gi), blk, 0, stream>>>(qkv, at, paccv,
                                                           paccs);
    merge_agent<<<dim3(Gi * Hh), blk, 0, stream>>>(paccv, paccs, av);
    // 4) fused q attention + dwc + pack -> Opk(=Apk)
    q_attn_dwc<<<dim3((Nn + 63) / 64, Hh, Gi), blk, 0, stream>>>(
        qkv, at, av, dwcw, dwcb, Apk);
    // 5) final projection -> out_g (+bias)
    {
      const int nch = Cc / 128;             // 6
      const int nwg = Mtiles * nch;
      gemm_pk2<<<dim3(nwg), blk, 0, stream>>>(Apk, WPpk, outg, bproj, Mg,
                                              Cc, nch, nwg);
    }
  }
}

// Round 14
// 821.484 us; speedup vs baseline: 1.0795x; 1.0795x over previous
//
#include <hip/hip_runtime.h>

namespace {

constexpr int Bb = 8;
constexpr int Nn = 4097;
constexpr int Cc = 768;
constexpr int Hh = 12;
constexpr int HD = 64;
constexpr int Aa = 49;
constexpr int LDQ = 3 * Cc;        // 2304 (qkv row stride)
constexpr int NCH = 16;            // j-chunks for agent attention
constexpr int CHUNK = (Nn + NCH - 1) / NCH;  // 257
constexpr float SCALE = 0.125f;    // hd^-0.5
constexpr int KP = 1536;           // packed plane row length (hi 768 | lo 768)

typedef short s16x8 __attribute__((ext_vector_type(8)));
typedef float f32x4 __attribute__((ext_vector_type(4)));

struct HL { short h, l; };

// Split fp32 into hi (truncated bf16, exact bits) + lo (RNE bf16 of residual).
__device__ inline HL splitbf(float v) {
  unsigned u = __float_as_uint(v);
  HL r;
  r.h = (short)(u >> 16);
  float hf = __uint_as_float(u & 0xffff0000u);
  float lf = v - hf;
  unsigned ul = __float_as_uint(lf);
  r.l = (short)((ul + 0x7fffu + ((ul >> 16) & 1u)) >> 16);
  return r;
}

__device__ inline unsigned short bf16rne(float v) {
  unsigned u = __float_as_uint(v);
  return (unsigned short)((u + 0x7fffu + ((u >> 16) & 1u)) >> 16);
}
__device__ inline float bf2f(unsigned short s) {
  return __uint_as_float((unsigned)s << 16);
}

// async global->LDS, 16B per lane (linear dest)
__device__ inline void gload16(const short* g, void* l) {
  __builtin_amdgcn_global_load_lds(
      (const __attribute__((address_space(1))) void*)g,
      (__attribute__((address_space(3))) void*)l, 16, 0, 0);
}

// Packed layout (R10/R12): per row, 12 windows of 64 elems (8 chunks of 8);
// physical chunk = logical chunk ^ (row&7). hi plane [0,768), lo [768,1536).

// ---------------------------------------------------------------------------
// Pack activations: src[M][768] fp32 -> dst[M][1536] bf16 = [hi | lo].
// ---------------------------------------------------------------------------
__global__ __launch_bounds__(256) void pack_act(
    const float* __restrict__ src, short* __restrict__ dst, int M) {
  int idx = blockIdx.x * 256 + threadIdx.x;
  if (idx >= M * 96) return;
  int m = idx / 96, kc = idx - m * 96;
  const float* s = src + (size_t)m * 768 + kc * 8;
  float4 v0 = *(const float4*)s;
  float4 v1 = *(const float4*)(s + 4);
  s16x8 hv, lv;
  HL r;
  r = splitbf(v0.x); hv[0] = r.h; lv[0] = r.l;
  r = splitbf(v0.y); hv[1] = r.h; lv[1] = r.l;
  r = splitbf(v0.z); hv[2] = r.h; lv[2] = r.l;
  r = splitbf(v0.w); hv[3] = r.h; lv[3] = r.l;
  r = splitbf(v1.x); hv[4] = r.h; lv[4] = r.l;
  r = splitbf(v1.y); hv[5] = r.h; lv[5] = r.l;
  r = splitbf(v1.z); hv[6] = r.h; lv[6] = r.l;
  r = splitbf(v1.w); hv[7] = r.h; lv[7] = r.l;
  int win = (kc >> 3) * 64;
  int jj = ((kc & 7) ^ (m & 7)) * 8;
  short* d = dst + (size_t)m * KP;
  *(s16x8*)&d[win + jj] = hv;
  *(s16x8*)&d[768 + win + jj] = lv;
}

// ---------------------------------------------------------------------------
// Pack weights: W[768][N] fp32 -> Wpk[N][1536] bf16, swizzle keyed (n&7).
// ---------------------------------------------------------------------------
__global__ __launch_bounds__(256) void pack_w(
    const float* __restrict__ W, short* __restrict__ Wpk, int N) {
  int idx = blockIdx.x * 256 + threadIdx.x;
  if (idx >= 96 * N) return;
  int kc = idx / N, n = idx - kc * N;
  s16x8 hv, lv;
#pragma unroll
  for (int i = 0; i < 8; ++i) {
    HL r = splitbf(W[(size_t)(kc * 8 + i) * N + n]);
    hv[i] = r.h; lv[i] = r.l;
  }
  int win = (kc >> 3) * 64;
  int jj = ((kc & 7) ^ (n & 7)) * 8;
  short* d = Wpk + (size_t)n * KP;
  *(s16x8*)&d[win + jj] = hv;
  *(s16x8*)&d[768 + win + jj] = lv;
}

// ---------------------------------------------------------------------------
// C[M x N] = A @ B (+bias) on packed planes. Per 64-K-chunk stage all four
// planes (64KB LDS), 96 mfma per barrier pair, 12 kt iterations.
// 1D grid with bijective XCD swizzle; n-fastest logical order.
// R12 structure — measured 297us/MfmaUtil 47%; both pipelining variants
// (BK=32 dbuf w/ __syncthreads R11, counted-vmcnt raw-barrier R13) regressed.
// ---------------------------------------------------------------------------
__global__ __launch_bounds__(256) void gemm_pk2(
    const short* __restrict__ Apk, const short* __restrict__ Bpk,
    float* __restrict__ Cm, const float* __restrict__ bias,
    int Mr, int ldc, int nch, int nwg) {
  __shared__ __align__(16) short AsH[128 * 64], AsL[128 * 64];
  __shared__ __align__(16) short BsH[128 * 64], BsL[128 * 64];
  const int t = threadIdx.x;
  const int lane = t & 63;
  const int w = t >> 6;
  const int wr = w >> 1, wc = w & 1;
  const int l15 = lane & 15, l4 = lane >> 4;

  const int j = blockIdx.x;
  const int q = nwg >> 3, r = nwg & 7;
  const int xcd = j & 7, pos = j >> 3;
  const int logical =
      (xcd < r ? xcd * (q + 1) : r * (q + 1) + (xcd - r) * q) + pos;
  const int mt = logical / nch, nc = logical - mt * nch;
  const int m0 = mt * 128, n0 = nc * 128;

  f32x4 acc[4][4];
#pragma unroll
  for (int mi = 0; mi < 4; ++mi)
#pragma unroll
    for (int ni = 0; ni < 4; ++ni) acc[mi][ni] = (f32x4){0.f, 0.f, 0.f, 0.f};

  for (int kt = 0; kt < 12; ++kt) {
    const short* Ab = Apk + (size_t)m0 * KP + kt * 64;
    const short* Bt = Bpk + (size_t)n0 * KP + kt * 64;
    __syncthreads();
#pragma unroll
    for (int i = 0; i < 4; ++i) {
      const int o = (i * 256 + t) * 16;   // byte offset in 16KB plane
      const int row = o >> 7;
      const int ce = (o & 127) >> 1;      // element col (physical)
      gload16(Ab + (size_t)row * KP + ce, (char*)AsH + o);
      gload16(Ab + (size_t)row * KP + 768 + ce, (char*)AsL + o);
      gload16(Bt + (size_t)row * KP + ce, (char*)BsH + o);
      gload16(Bt + (size_t)row * KP + 768 + ce, (char*)BsL + o);
    }
    __syncthreads();
#pragma unroll
    for (int ks = 0; ks < 2; ++ks) {
      s16x8 ah[4], al[4], bh[4], bl[4];
#pragma unroll
      for (int mi = 0; mi < 4; ++mi) {
        int rr = wr * 64 + mi * 16 + l15;
        int off = rr * 64 + ((((ks << 2) + l4) ^ (l15 & 7)) << 3);
        ah[mi] = *(const s16x8*)&AsH[off];
        al[mi] = *(const s16x8*)&AsL[off];
      }
#pragma unroll
      for (int ni = 0; ni < 4; ++ni) {
        int rr = wc * 64 + ni * 16 + l15;
        int off = rr * 64 + ((((ks << 2) + l4) ^ (l15 & 7)) << 3);
        bh[ni] = *(const s16x8*)&BsH[off];
        bl[ni] = *(const s16x8*)&BsL[off];
      }
#pragma unroll
      for (int mi = 0; mi < 4; ++mi)
#pragma unroll
        for (int ni = 0; ni < 4; ++ni) {
          acc[mi][ni] = __builtin_amdgcn_mfma_f32_16x16x32_bf16(
              ah[mi], bh[ni], acc[mi][ni], 0, 0, 0);
          acc[mi][ni] = __builtin_amdgcn_mfma_f32_16x16x32_bf16(
              ah[mi], bl[ni], acc[mi][ni], 0, 0, 0);
          acc[mi][ni] = __builtin_amdgcn_mfma_f32_16x16x32_bf16(
              al[mi], bh[ni], acc[mi][ni], 0, 0, 0);
        }
    }
  }

#pragma unroll
  for (int mi = 0; mi < 4; ++mi) {
#pragma unroll
    for (int jr = 0; jr < 4; ++jr) {
      int gr = m0 + wr * 64 + mi * 16 + l4 * 4 + jr;
      if (gr < Mr) {
#pragma unroll
        for (int ni = 0; ni < 4; ++ni) {
          int gc = n0 + wc * 64 + ni * 16 + l15;
          float v = acc[mi][ni][jr];
          if (bias) v += bias[gc];
          Cm[(size_t)gr * ldc + gc] = v;
        }
      }
    }
  }
}

// ---------------------------------------------------------------------------
// Adaptive-pool agents: at[bg,a,c] = mean over q rows [s,e) of q[bg,l,c].
// ---------------------------------------------------------------------------
__global__ __launch_bounds__(192) void pool_agents(
    const float* __restrict__ qkv, float* __restrict__ at) {
  const int ba = blockIdx.x;
  const int bg = ba / Aa, a = ba % Aa;
  const int s = (a * 4096) / 49;
  const int e = ((a + 1) * 4096 + 48) / 49;
  const float w = 1.0f / (float)(e - s);
  const int c4 = threadIdx.x * 4;
  f32x4 sum = (f32x4){0.f, 0.f, 0.f, 0.f};
#pragma unroll 4
  for (int l = s; l < e; ++l) {
    const float4 v = *(const float4*)&qkv[(size_t)(bg * Nn + l) * LDQ + c4];
    sum[0] += v.x; sum[1] += v.y; sum[2] += v.z; sum[3] += v.w;
  }
  float4 o;
  o.x = sum[0] * w; o.y = sum[1] * w; o.z = sum[2] * w; o.w = sum[3] * w;
  *(float4*)&at[(size_t)(bg * Aa + a) * Cc + c4] = o;
}

// ---------------------------------------------------------------------------
// Agent attention via MFMA split-bf16. 48KB LDS, P aliases K planes.
// 3 barriers/tile: the old 4th barrier (P-write -> PV) was removed — P's
// write rows (w*16 + l4*4+reg) and PV's A-frag read rows (w*16 + l15) are the
// SAME wave-local 16-row slice, so no cross-wave ordering is needed there;
// the pre-P-write barrier already protects other waves' K reads.
// ---------------------------------------------------------------------------
__global__ __launch_bounds__(256) void agent_attn_mfma(
    const float* __restrict__ qkv, const float* __restrict__ at,
    float* __restrict__ paccv, float* __restrict__ paccs) {
  const int chunk = blockIdx.x, h = blockIdx.y, bg = blockIdx.z;
  __shared__ __align__(16) short AhH[4096], AhL[4096];  // ah [a][d]
  __shared__ __align__(16) short KH[4096], KL[4096];    // K [j][d]; P aliases
  __shared__ __align__(16) short VtH[4096], VtL[4096];  // V^T [c][j]
  const int t = threadIdx.x;
  const int w = t >> 6, lane = t & 63, l15 = lane & 15, l4 = lane >> 4;

  for (int idx = t; idx < 512; idx += 256) {
    int a = idx >> 3, c8 = idx & 7;
    float vals[8];
    if (a < Aa) {
      const float* src = &at[(size_t)(bg * Aa + a) * Cc + h * HD + c8 * 8];
      *(float4*)&vals[0] = *(const float4*)src;
      *(float4*)&vals[4] = *(const float4*)(src + 4);
    } else {
#pragma unroll
      for (int i = 0; i < 8; ++i) vals[i] = 0.f;
    }
    s16x8 hv, lv;
#pragma unroll
    for (int i = 0; i < 8; ++i) {
      HL r = splitbf(vals[i]);
      hv[i] = r.h; lv[i] = r.l;
    }
    int pos = a * 64 + ((c8 ^ (a & 7)) << 3);
    *(s16x8*)&AhH[pos] = hv;
    *(s16x8*)&AhL[pos] = lv;
  }

  f32x4 acc[4];
#pragma unroll
  for (int ni = 0; ni < 4; ++ni) acc[ni] = (f32x4){0.f, 0.f, 0.f, 0.f};
  float rs[4] = {0.f, 0.f, 0.f, 0.f};

  const int jstart = chunk * CHUNK;
  const int jend = min(jstart + CHUNK, Nn);
  const int srow = t >> 2, sc0 = (t & 3) * 16;

  for (int j0 = jstart; j0 < jend; j0 += 64) {
    __syncthreads();   // prev tile's S (K reads) + PV (P/V reads) done
    {
      int jg = j0 + srow;
      float kv[16], vv[16];
      if (jg < jend) {
        const float* p = &qkv[(size_t)(bg * Nn + jg) * LDQ + Cc + h * HD + sc0];
#pragma unroll
        for (int r = 0; r < 4; ++r) {
          *(float4*)&kv[r * 4] = *(const float4*)(p + r * 4);
          *(float4*)&vv[r * 4] = *(const float4*)(p + Cc + r * 4);
        }
      } else {
#pragma unroll
        for (int i = 0; i < 16; ++i) { kv[i] = 0.f; vv[i] = 0.f; }
      }
#pragma unroll
      for (int r = 0; r < 2; ++r) {
        s16x8 hv, lv;
#pragma unroll
        for (int i = 0; i < 8; ++i) {
          HL s = splitbf(kv[r * 8 + i]);
          hv[i] = s.h; lv[i] = s.l;
        }
        int ch = (sc0 >> 3) + r;
        int pos = srow * 64 + ((ch ^ (srow & 7)) << 3);
        *(s16x8*)&KH[pos] = hv;
        *(s16x8*)&KL[pos] = lv;
      }
#pragma unroll
      for (int i = 0; i < 16; ++i) {
        HL s = splitbf(vv[i]);
        int c = sc0 + i;
        int pos = c * 64 + ((((srow >> 3) ^ (c & 7)) << 3)) + (srow & 7);
        VtH[pos] = s.h;
        VtL[pos] = s.l;
      }
    }
    __syncthreads();   // staged K/V visible to all waves

    f32x4 s[4];
#pragma unroll
    for (int ni = 0; ni < 4; ++ni) s[ni] = (f32x4){0.f, 0.f, 0.f, 0.f};
#pragma unroll
    for (int ks = 0; ks < 2; ++ks) {
      int sw = (((ks << 2) + l4) ^ (l15 & 7)) << 3;
      s16x8 ahh = *(const s16x8*)&AhH[(w * 16 + l15) * 64 + sw];
      s16x8 ahl = *(const s16x8*)&AhL[(w * 16 + l15) * 64 + sw];
#pragma unroll
      for (int ni = 0; ni < 4; ++ni) {
        s16x8 kh = *(const s16x8*)&KH[(ni * 16 + l15) * 64 + sw];
        s16x8 kl = *(const s16x8*)&KL[(ni * 16 + l15) * 64 + sw];
        s[ni] = __builtin_amdgcn_mfma_f32_16x16x32_bf16(ahh, kh, s[ni], 0, 0, 0);
        s[ni] = __builtin_amdgcn_mfma_f32_16x16x32_bf16(ahh, kl, s[ni], 0, 0, 0);
        s[ni] = __builtin_amdgcn_mfma_f32_16x16x32_bf16(ahl, kh, s[ni], 0, 0, 0);
      }
    }
    __syncthreads();   // all waves done reading K -> P may overwrite K planes

    // P = exp (masked); transpose-write into K planes. Wave-local rows:
    // write rows w*16+l4*4+reg == read rows w*16+l15 below -> no barrier.
#pragma unroll
    for (int ni = 0; ni < 4; ++ni) {
#pragma unroll
      for (int reg = 0; reg < 4; ++reg) {
        int jj = l15 + 16 * ni;
        float pv = (j0 + jj < jend) ? expf(s[ni][reg] * SCALE) : 0.f;
        rs[reg] += pv;
        HL r = splitbf(pv);
        int a = w * 16 + l4 * 4 + reg;
        int pos = a * 64 + ((((jj >> 3) ^ (a & 7)) << 3)) + (jj & 7);
        KH[pos] = r.h;
        KL[pos] = r.l;
      }
    }

    // O += P @ V (P reads wave-local, compiler orders LDS within wave)
#pragma unroll
    for (int ks = 0; ks < 2; ++ks) {
      int sw = (((ks << 2) + l4) ^ (l15 & 7)) << 3;
      s16x8 ph = *(const s16x8*)&KH[(w * 16 + l15) * 64 + sw];
      s16x8 pl = *(const s16x8*)&KL[(w * 16 + l15) * 64 + sw];
#pragma unroll
      for (int ni = 0; ni < 4; ++ni) {
        s16x8 vh = *(const s16x8*)&VtH[(ni * 16 + l15) * 64 + sw];
        s16x8 vl = *(const s16x8*)&VtL[(ni * 16 + l15) * 64 + sw];
        acc[ni] = __builtin_amdgcn_mfma_f32_16x16x32_bf16(ph, vh, acc[ni], 0, 0, 0);
        acc[ni] = __builtin_amdgcn_mfma_f32_16x16x32_bf16(ph, vl, acc[ni], 0, 0, 0);
        acc[ni] = __builtin_amdgcn_mfma_f32_16x16x32_bf16(pl, vh, acc[ni], 0, 0, 0);
      }
    }
  }

#pragma unroll
  for (int reg = 0; reg < 4; ++reg) {
    rs[reg] += __shfl_xor(rs[reg], 1);
    rs[reg] += __shfl_xor(rs[reg], 2);
    rs[reg] += __shfl_xor(rs[reg], 4);
    rs[reg] += __shfl_xor(rs[reg], 8);
  }
  const int basev = ((bg * Hh + h) * NCH + chunk) * (Aa * 64);
#pragma unroll
  for (int reg = 0; reg < 4; ++reg) {
    int a = w * 16 + l4 * 4 + reg;
    if (a < Aa) {
#pragma unroll
      for (int ni = 0; ni < 4; ++ni)
        paccv[basev + a * 64 + l15 + 16 * ni] = acc[ni][reg];
      if (l15 == 0)
        paccs[((bg * Hh + h) * NCH + chunk) * Aa + a] = rs[reg];
    }
  }
}

// ---------------------------------------------------------------------------
// Merge chunk partials -> agent_v[bgh,a,c]
// ---------------------------------------------------------------------------
__global__ __launch_bounds__(256) void merge_agent(
    const float* __restrict__ paccv, const float* __restrict__ paccs,
    float* __restrict__ av) {
  const int bh = blockIdx.x;
  const int t = threadIdx.x;
  for (int idx = t; idx < Aa * HD; idx += 256) {
    int a = idx >> 6;
    float vs = 0.f, ss = 0.f;
#pragma unroll
    for (int ch = 0; ch < NCH; ++ch) {
      vs += paccv[(size_t)((bh * NCH + ch)) * (Aa * 64) + idx];
      ss += paccs[(bh * NCH + ch) * Aa + a];
    }
    av[(size_t)bh * (Aa * HD) + idx] = vs / ss;
  }
}

// ---------------------------------------------------------------------------
// FUSED q attention + dwc + split-pack. Vectorized epilogue: O -> LDS,
// re-gather into whole 8-channel chunks -> 16B coalesced stores (R12 layout:
// win = h*64, jj = (kc ^ (mrow&7))*8).
// ---------------------------------------------------------------------------
__global__ __launch_bounds__(256) void q_attn_dwc(
    const float* __restrict__ qkv, const float* __restrict__ at,
    const float* __restrict__ av, const float* __restrict__ dwcw,
    const float* __restrict__ dwcb, short* __restrict__ Opk) {
  const int i0 = blockIdx.x * 64, h = blockIdx.y, bg = blockIdx.z;
  __shared__ __align__(16) short SMEM[24576];   // 48KB
  short* AhH = SMEM;             // [a][d] ; olds aliases after PV
  short* AhL = SMEM + 4096;
  short* AvH = SMEM + 8192;      // av^T [c][a]
  short* AvL = SMEM + 12288;
  short* QH  = SMEM + 16384;     // q [row][d]; P alias; v-stage alias
  short* QL  = SMEM + 20480;
  const int t = threadIdx.x;
  const int w = t >> 6, lane = t & 63, l15 = lane & 15, l4 = lane >> 4;

  for (int idx = t; idx < 512; idx += 256) {
    int a = idx >> 3, c8 = idx & 7;
    float vah[8], vav[8];
    if (a < Aa) {
      const float* s1 = &at[(size_t)(bg * Aa + a) * Cc + h * HD + c8 * 8];
      const float* s2 = &av[(size_t)(bg * Hh + h) * (Aa * HD) + a * HD + c8 * 8];
      *(float4*)&vah[0] = *(const float4*)s1;
      *(float4*)&vah[4] = *(const float4*)(s1 + 4);
      *(float4*)&vav[0] = *(const float4*)s2;
      *(float4*)&vav[4] = *(const float4*)(s2 + 4);
    } else {
#pragma unroll
      for (int i = 0; i < 8; ++i) { vah[i] = 0.f; vav[i] = 0.f; }
    }
    s16x8 hv, lv;
#pragma unroll
    for (int i = 0; i < 8; ++i) {
      HL r = splitbf(vah[i]);
      hv[i] = r.h; lv[i] = r.l;
    }
    int pos = a * 64 + ((c8 ^ (a & 7)) << 3);
    *(s16x8*)&AhH[pos] = hv;
    *(s16x8*)&AhL[pos] = lv;
#pragma unroll
    for (int i = 0; i < 8; ++i) {
      HL r = splitbf(vav[i]);
      int c = c8 * 8 + i;
      int pos2 = c * 64 + ((((a >> 3) ^ (c & 7)) << 3)) + (a & 7);
      AvH[pos2] = r.h;
      AvL[pos2] = r.l;
    }
  }
  {
    int row = t >> 2, c0 = (t & 3) * 16;
    int ig = i0 + row;
    float qv[16];
    if (ig < Nn) {
      const float* p = &qkv[(size_t)(bg * Nn + ig) * LDQ + h * HD + c0];
#pragma unroll
      for (int r = 0; r < 4; ++r) *(float4*)&qv[r * 4] = *(const float4*)(p + r * 4);
    } else {
#pragma unroll
      for (int i = 0; i < 16; ++i) qv[i] = 0.f;
    }
#pragma unroll
    for (int r = 0; r < 2; ++r) {
      s16x8 hv, lv;
#pragma unroll
      for (int i = 0; i < 8; ++i) {
        HL s = splitbf(qv[r * 8 + i]);
        hv[i] = s.h; lv[i] = s.l;
      }
      int ch = (c0 >> 3) + r;
      int pos = row * 64 + ((ch ^ (row & 7)) << 3);
      *(s16x8*)&QH[pos] = hv;
      *(s16x8*)&QL[pos] = lv;
    }
  }
  __syncthreads();

  // ---- S = q @ ah^T ----
  f32x4 s[4];
#pragma unroll
  for (int ni = 0; ni < 4; ++ni) s[ni] = (f32x4){0.f, 0.f, 0.f, 0.f};
#pragma unroll
  for (int ks = 0; ks < 2; ++ks) {
    int sw = (((ks << 2) + l4) ^ (l15 & 7)) << 3;
    s16x8 qh = *(const s16x8*)&QH[(w * 16 + l15) * 64 + sw];
    s16x8 ql = *(const s16x8*)&QL[(w * 16 + l15) * 64 + sw];
#pragma unroll
    for (int ni = 0; ni < 4; ++ni) {
      s16x8 bh = *(const s16x8*)&AhH[(ni * 16 + l15) * 64 + sw];
      s16x8 bl = *(const s16x8*)&AhL[(ni * 16 + l15) * 64 + sw];
      s[ni] = __builtin_amdgcn_mfma_f32_16x16x32_bf16(qh, bh, s[ni], 0, 0, 0);
      s[ni] = __builtin_amdgcn_mfma_f32_16x16x32_bf16(qh, bl, s[ni], 0, 0, 0);
      s[ni] = __builtin_amdgcn_mfma_f32_16x16x32_bf16(ql, bh, s[ni], 0, 0, 0);
    }
  }
  __syncthreads();

  // ---- softmax over agents + transpose-write P into Q planes ----
  float rsum[4] = {0.f, 0.f, 0.f, 0.f};
#pragma unroll
  for (int ni = 0; ni < 4; ++ni) {
#pragma unroll
    for (int reg = 0; reg < 4; ++reg) {
      int a = l15 + 16 * ni;
      float pv = (a < Aa) ? expf(s[ni][reg] * SCALE) : 0.f;
      s[ni][reg] = pv;
      rsum[reg] += pv;
    }
  }
#pragma unroll
  for (int reg = 0; reg < 4; ++reg) {
    rsum[reg] += __shfl_xor(rsum[reg], 1);
    rsum[reg] += __shfl_xor(rsum[reg], 2);
    rsum[reg] += __shfl_xor(rsum[reg], 4);
    rsum[reg] += __shfl_xor(rsum[reg], 8);
    rsum[reg] = 1.0f / rsum[reg];
  }
#pragma unroll
  for (int ni = 0; ni < 4; ++ni) {
#pragma unroll
    for (int reg = 0; reg < 4; ++reg) {
      HL r = splitbf(s[ni][reg] * rsum[reg]);
      int row = w * 16 + l4 * 4 + reg;
      int a = l15 + 16 * ni;
      int pos = row * 64 + ((((a >> 3) ^ (row & 7)) << 3)) + (a & 7);
      QH[pos] = r.h;
      QL[pos] = r.l;
    }
  }
  __syncthreads();

  // ---- O = P @ agent_v ----
  f32x4 o[4];
#pragma unroll
  for (int ni = 0; ni < 4; ++ni) o[ni] = (f32x4){0.f, 0.f, 0.f, 0.f};
#pragma unroll
  for (int ks = 0; ks < 2; ++ks) {
    int sw = (((ks << 2) + l4) ^ (l15 & 7)) << 3;
    s16x8 ph = *(const s16x8*)&QH[(w * 16 + l15) * 64 + sw];
    s16x8 pl = *(const s16x8*)&QL[(w * 16 + l15) * 64 + sw];
#pragma unroll
    for (int ni = 0; ni < 4; ++ni) {
      s16x8 vh = *(const s16x8*)&AvH[(ni * 16 + l15) * 64 + sw];
      s16x8 vl = *(const s16x8*)&AvL[(ni * 16 + l15) * 64 + sw];
      o[ni] = __builtin_amdgcn_mfma_f32_16x16x32_bf16(ph, vh, o[ni], 0, 0, 0);
      o[ni] = __builtin_amdgcn_mfma_f32_16x16x32_bf16(ph, vl, o[ni], 0, 0, 0);
      o[ni] = __builtin_amdgcn_mfma_f32_16x16x32_bf16(pl, vh, o[ni], 0, 0, 0);
    }
  }
  __syncthreads();  // all LDS dead -> olds / vlds may overwrite

  // ---- write O to LDS (stride 68) + stage v tile (bf16) ----
  float* olds = (float*)SMEM;                        // 64*68*4 = 17408B
  unsigned short* vlds = (unsigned short*)QH;        // 66*72*2 = 9504B
#pragma unroll
  for (int reg = 0; reg < 4; ++reg) {
    int row = w * 16 + l4 * 4 + reg;
#pragma unroll
    for (int ni = 0; ni < 4; ++ni)
      olds[row * 68 + l15 + 16 * ni] = o[ni][reg];
  }
  constexpr int VLD = 72;
  for (int idx = t; idx < 66 * 16; idx += 256) {
    int row = idx >> 4, cs = (idx & 15) << 2;
    int gr = i0 - 1 + row;
    float4 v = make_float4(0.f, 0.f, 0.f, 0.f);
    if (gr >= 0 && gr < 4096)
      v = *(const float4*)&qkv[((size_t)bg * Nn + gr) * LDQ + 2 * Cc + h * HD + cs];
    unsigned short* d = &vlds[row * VLD + cs];
    d[0] = bf16rne(v.x); d[1] = bf16rne(v.y);
    d[2] = bf16rne(v.z); d[3] = bf16rne(v.w);
  }
  __syncthreads();

  // ---- re-gather: (local row, 8-ch chunk) -> 16B stores, R12 layout ----
#pragma unroll
  for (int it = 0; it < 2; ++it) {
    int widx = t + it * 256;            // 0..511
    int ml = widx >> 3, kc = widx & 7;
    int ig = i0 + ml;
    if (ig >= Nn) continue;
    float vals[8];
    *(float4*)&vals[0] = *(const float4*)&olds[ml * 68 + kc * 8];
    *(float4*)&vals[4] = *(const float4*)&olds[ml * 68 + kc * 8 + 4];
    if (ig < Nn - 1) {
      const int rl = ml + 1;
      const unsigned short* vr = &vlds[rl * VLD + kc * 8];
#pragma unroll
      for (int cI = 0; cI < 8; ++cI) {
        int cg = h * HD + kc * 8 + cI;
        float vm = bf2f(vr[cI - VLD]);
        float v0 = bf2f(vr[cI]);
        float vp = bf2f(vr[cI + VLD]);
        vals[cI] += dwcw[cg * 3] * vm + dwcw[cg * 3 + 1] * v0 +
                    dwcw[cg * 3 + 2] * vp + dwcb[cg];
      }
    }
    s16x8 hv, lv;
#pragma unroll
    for (int cI = 0; cI < 8; ++cI) {
      HL r = splitbf(vals[cI]);
      hv[cI] = r.h; lv[cI] = r.l;
    }
    const int mrow = bg * Nn + ig;
    const int win = h * 64;                        // (kcg>>3)*64, kcg=h*8+kc
    const int jj = (kc ^ (mrow & 7)) * 8;
    *(s16x8*)&Opk[(size_t)mrow * KP + win + jj] = hv;
    *(s16x8*)&Opk[(size_t)mrow * KP + 768 + win + jj] = lv;
  }
}

}  // namespace

extern "C" void kernel_launch(void* const* d_in, const int* in_sizes, int n_in,
                              void* d_out, int out_size, void* d_ws,
                              size_t ws_size, hipStream_t stream) {
  const float* x = (const float*)d_in[0];
  const float* Wqkv = (const float*)d_in[1];
  const float* Wproj = (const float*)d_in[2];
  const float* bproj = (const float*)d_in[3];
  const float* dwcw = (const float*)d_in[4];
  const float* dwcb = (const float*)d_in[5];
  float* out = (float*)d_out;

  // --- fixed workspace: packed weight planes ---
  char* p = (char*)d_ws;
  short* WQpk = (short*)p; p += (size_t)LDQ * KP * 2;   // 7,077,888 B
  short* WPpk = (short*)p; p += (size_t)Cc * KP * 2;    // 2,359,296 B
  const size_t fixedBytes = (size_t)p - (size_t)d_ws;

  auto bytesFor = [&](int G) -> size_t {
    size_t Mg = (size_t)G * Nn;
    size_t Mpad = ((Mg + 127) / 128) * 128;
    size_t fl = Mg * LDQ +
                (size_t)G * (Aa * Cc + Hh * NCH * Aa * 64 + Hh * NCH * Aa +
                             Hh * Aa * HD);
    return fixedBytes + fl * 4 + Mpad * KP * 2;            // + Apk/Opk
  };
  int G = 1;
  for (int g = Bb; g >= 1; --g) {
    if (bytesFor(g) <= ws_size) { G = g; break; }
  }

  const size_t MgMax = (size_t)G * Nn;
  float* qkv = (float*)p;
  float* at = qkv + MgMax * LDQ;
  float* paccv = at + (size_t)G * Aa * Cc;
  float* paccs = paccv + (size_t)G * Hh * NCH * Aa * 64;
  float* av = paccs + (size_t)G * Hh * NCH * Aa;
  short* Apk = (short*)(av + (size_t)G * Hh * Aa * HD);   // aliased as Opk

  dim3 blk(256);
  // 0) pack weights (once per launch; deterministic)
  pack_w<<<dim3((96 * LDQ + 255) / 256), blk, 0, stream>>>(Wqkv, WQpk, LDQ);
  pack_w<<<dim3((96 * Cc + 255) / 256), blk, 0, stream>>>(Wproj, WPpk, Cc);

  for (int b0 = 0; b0 < Bb; b0 += G) {
    const int Gi = (b0 + G <= Bb) ? G : (Bb - b0);
    const int Mg = Gi * Nn;
    const int Mtiles = (Mg + 127) / 128;
    const float* xg = x + (size_t)b0 * Nn * Cc;
    float* outg = out + (size_t)b0 * Nn * Cc;

    // 1) pack x -> Apk, then qkv = x @ Wqkv (packed MFMA GEMM)
    pack_act<<<dim3((Mg * 96 + 255) / 256), blk, 0, stream>>>(xg, Apk, Mg);
    {
      const int nch = LDQ / 128;            // 18
      const int nwg = Mtiles * nch;
      gemm_pk2<<<dim3(nwg), blk, 0, stream>>>(Apk, WQpk, qkv, nullptr, Mg,
                                              LDQ, nch, nwg);
    }
    // 2) agent tokens (adaptive pool of q)
    pool_agents<<<dim3(Gi * Aa), dim3(192), 0, stream>>>(qkv, at);
    // 3) agent attention partials (MFMA) + merge -> agent_v
    agent_attn_mfma<<<dim3(NCH, Hh, Gi), blk, 0, stream>>>(qkv, at, paccv,
                                                           paccs);
    merge_agent<<<dim3(Gi * Hh), blk, 0, stream>>>(paccv, paccs, av);
    // 4) fused q attention + dwc + pack -> Opk(=Apk)
    q_attn_dwc<<<dim3((Nn + 63) / 64, Hh, Gi), blk, 0, stream>>>(
        qkv, at, av, dwcw, dwcb, Apk);
    // 5) final projection -> out_g (+bias)
    {
      const int nch = Cc / 128;             // 6
      const int nwg = Mtiles * nch;
      gemm_pk2<<<dim3(nwg), blk, 0, stream>>>(Apk, WPpk, outg, bproj, Mg,
                                              Cc, nch, nwg);
    }
  }
}

// Round 15
// 762.525 us; speedup vs baseline: 1.1630x; 1.0773x over previous
//
#include <hip/hip_runtime.h>

namespace {

constexpr int Bb = 8;
constexpr int Nn = 4097;
constexpr int Cc = 768;
constexpr int Hh = 12;
constexpr int HD = 64;
constexpr int Aa = 49;
constexpr int LDQ = 3 * Cc;        // 2304 (qkv row stride)
constexpr int NCH = 16;            // j-chunks for agent attention
constexpr int CHUNK = 256;         // 64-aligned; last chunk absorbs row 4096
constexpr float SCALE = 0.125f;    // hd^-0.5
constexpr int KP = 1536;           // packed plane row length (hi 768 | lo 768)

typedef short s16x8 __attribute__((ext_vector_type(8)));
typedef float f32x4 __attribute__((ext_vector_type(4)));

struct HL { short h, l; };

// Split fp32 into hi (truncated bf16, exact bits) + lo (RNE bf16 of residual).
__device__ inline HL splitbf(float v) {
  unsigned u = __float_as_uint(v);
  HL r;
  r.h = (short)(u >> 16);
  float hf = __uint_as_float(u & 0xffff0000u);
  float lf = v - hf;
  unsigned ul = __float_as_uint(lf);
  r.l = (short)((ul + 0x7fffu + ((ul >> 16) & 1u)) >> 16);
  return r;
}

__device__ inline unsigned short bf16rne(float v) {
  unsigned u = __float_as_uint(v);
  return (unsigned short)((u + 0x7fffu + ((u >> 16) & 1u)) >> 16);
}
__device__ inline float bf2f(unsigned short s) {
  return __uint_as_float((unsigned)s << 16);
}

// async global->LDS, 16B per lane (linear dest)
__device__ inline void gload16(const short* g, void* l) {
  __builtin_amdgcn_global_load_lds(
      (const __attribute__((address_space(1))) void*)g,
      (__attribute__((address_space(3))) void*)l, 16, 0, 0);
}

// Packed layout: per row, 12 windows of 64 elems (8 chunks of 8);
// physical chunk = logical chunk ^ (row&7). hi plane [0,768), lo [768,1536).

// ---------------------------------------------------------------------------
// Pack activations: src[M][768] fp32 -> dst[M][1536] bf16 = [hi | lo].
// ---------------------------------------------------------------------------
__global__ __launch_bounds__(256) void pack_act(
    const float* __restrict__ src, short* __restrict__ dst, int M) {
  int idx = blockIdx.x * 256 + threadIdx.x;
  if (idx >= M * 96) return;
  int m = idx / 96, kc = idx - m * 96;
  const float* s = src + (size_t)m * 768 + kc * 8;
  float4 v0 = *(const float4*)s;
  float4 v1 = *(const float4*)(s + 4);
  s16x8 hv, lv;
  HL r;
  r = splitbf(v0.x); hv[0] = r.h; lv[0] = r.l;
  r = splitbf(v0.y); hv[1] = r.h; lv[1] = r.l;
  r = splitbf(v0.z); hv[2] = r.h; lv[2] = r.l;
  r = splitbf(v0.w); hv[3] = r.h; lv[3] = r.l;
  r = splitbf(v1.x); hv[4] = r.h; lv[4] = r.l;
  r = splitbf(v1.y); hv[5] = r.h; lv[5] = r.l;
  r = splitbf(v1.z); hv[6] = r.h; lv[6] = r.l;
  r = splitbf(v1.w); hv[7] = r.h; lv[7] = r.l;
  int win = (kc >> 3) * 64;
  int jj = ((kc & 7) ^ (m & 7)) * 8;
  short* d = dst + (size_t)m * KP;
  *(s16x8*)&d[win + jj] = hv;
  *(s16x8*)&d[768 + win + jj] = lv;
}

// ---------------------------------------------------------------------------
// Pack weights: W[768][N] fp32 -> Wpk[N][1536] bf16, swizzle keyed (n&7).
// ---------------------------------------------------------------------------
__global__ __launch_bounds__(256) void pack_w(
    const float* __restrict__ W, short* __restrict__ Wpk, int N) {
  int idx = blockIdx.x * 256 + threadIdx.x;
  if (idx >= 96 * N) return;
  int kc = idx / N, n = idx - kc * N;
  s16x8 hv, lv;
#pragma unroll
  for (int i = 0; i < 8; ++i) {
    HL r = splitbf(W[(size_t)(kc * 8 + i) * N + n]);
    hv[i] = r.h; lv[i] = r.l;
  }
  int win = (kc >> 3) * 64;
  int jj = ((kc & 7) ^ (n & 7)) * 8;
  short* d = Wpk + (size_t)n * KP;
  *(s16x8*)&d[win + jj] = hv;
  *(s16x8*)&d[768 + win + jj] = lv;
}

// ---------------------------------------------------------------------------
// C[M x N] = A @ B (+bias) on packed planes. R12 structure (frozen; both
// pipelining variants regressed). NEW: precision tiers — n-tiles with
// n0 < vstart are SCORE tiles (q,k): 2 products (ah*bh + ah*bl; A truncated
// bf16, B full) and the A-lo plane is not staged. n0 >= vstart (v / proj):
// full 3-product split, bit-identical to R12/R14. Per-element accumulation
// order for full tiles unchanged (bh, bl, then al*bh).
// ---------------------------------------------------------------------------
__global__ __launch_bounds__(256) void gemm_pk2(
    const short* __restrict__ Apk, const short* __restrict__ Bpk,
    float* __restrict__ Cm, const float* __restrict__ bias,
    int Mr, int ldc, int nch, int nwg, int vstart) {
  __shared__ __align__(16) short AsH[128 * 64], AsL[128 * 64];
  __shared__ __align__(16) short BsH[128 * 64], BsL[128 * 64];
  const int t = threadIdx.x;
  const int lane = t & 63;
  const int w = t >> 6;
  const int wr = w >> 1, wc = w & 1;
  const int l15 = lane & 15, l4 = lane >> 4;

  const int j = blockIdx.x;
  const int q = nwg >> 3, r = nwg & 7;
  const int xcd = j & 7, pos = j >> 3;
  const int logical =
      (xcd < r ? xcd * (q + 1) : r * (q + 1) + (xcd - r) * q) + pos;
  const int mt = logical / nch, nc = logical - mt * nch;
  const int m0 = mt * 128, n0 = nc * 128;
  const bool full = (n0 >= vstart);   // value-path tile -> 3-product split

  f32x4 acc[4][4];
#pragma unroll
  for (int mi = 0; mi < 4; ++mi)
#pragma unroll
    for (int ni = 0; ni < 4; ++ni) acc[mi][ni] = (f32x4){0.f, 0.f, 0.f, 0.f};

  for (int kt = 0; kt < 12; ++kt) {
    const short* Ab = Apk + (size_t)m0 * KP + kt * 64;
    const short* Bt = Bpk + (size_t)n0 * KP + kt * 64;
    __syncthreads();
#pragma unroll
    for (int i = 0; i < 4; ++i) {
      const int o = (i * 256 + t) * 16;   // byte offset in 16KB plane
      const int row = o >> 7;
      const int ce = (o & 127) >> 1;      // element col (physical)
      gload16(Ab + (size_t)row * KP + ce, (char*)AsH + o);
      gload16(Bt + (size_t)row * KP + ce, (char*)BsH + o);
      gload16(Bt + (size_t)row * KP + 768 + ce, (char*)BsL + o);
      if (full) gload16(Ab + (size_t)row * KP + 768 + ce, (char*)AsL + o);
    }
    __syncthreads();
#pragma unroll
    for (int ks = 0; ks < 2; ++ks) {
      s16x8 ah[4], al[4], bh[4], bl[4];
#pragma unroll
      for (int mi = 0; mi < 4; ++mi) {
        int rr = wr * 64 + mi * 16 + l15;
        int off = rr * 64 + ((((ks << 2) + l4) ^ (l15 & 7)) << 3);
        ah[mi] = *(const s16x8*)&AsH[off];
        if (full) al[mi] = *(const s16x8*)&AsL[off];
      }
#pragma unroll
      for (int ni = 0; ni < 4; ++ni) {
        int rr = wc * 64 + ni * 16 + l15;
        int off = rr * 64 + ((((ks << 2) + l4) ^ (l15 & 7)) << 3);
        bh[ni] = *(const s16x8*)&BsH[off];
        bl[ni] = *(const s16x8*)&BsL[off];
      }
#pragma unroll
      for (int mi = 0; mi < 4; ++mi)
#pragma unroll
        for (int ni = 0; ni < 4; ++ni) {
          acc[mi][ni] = __builtin_amdgcn_mfma_f32_16x16x32_bf16(
              ah[mi], bh[ni], acc[mi][ni], 0, 0, 0);
          acc[mi][ni] = __builtin_amdgcn_mfma_f32_16x16x32_bf16(
              ah[mi], bl[ni], acc[mi][ni], 0, 0, 0);
        }
      if (full) {
#pragma unroll
        for (int mi = 0; mi < 4; ++mi)
#pragma unroll
          for (int ni = 0; ni < 4; ++ni)
            acc[mi][ni] = __builtin_amdgcn_mfma_f32_16x16x32_bf16(
                al[mi], bh[ni], acc[mi][ni], 0, 0, 0);
      }
    }
  }

#pragma unroll
  for (int mi = 0; mi < 4; ++mi) {
#pragma unroll
    for (int jr = 0; jr < 4; ++jr) {
      int gr = m0 + wr * 64 + mi * 16 + l4 * 4 + jr;
      if (gr < Mr) {
#pragma unroll
        for (int ni = 0; ni < 4; ++ni) {
          int gc = n0 + wc * 64 + ni * 16 + l15;
          float v = acc[mi][ni][jr];
          if (bias) v += bias[gc];
          Cm[(size_t)gr * ldc + gc] = v;
        }
      }
    }
  }
}

// ---------------------------------------------------------------------------
// Adaptive-pool agents: at[bg,a,c] = mean over q rows [s,e) of q[bg,l,c].
// ---------------------------------------------------------------------------
__global__ __launch_bounds__(192) void pool_agents(
    const float* __restrict__ qkv, float* __restrict__ at) {
  const int ba = blockIdx.x;
  const int bg = ba / Aa, a = ba % Aa;
  const int s = (a * 4096) / 49;
  const int e = ((a + 1) * 4096 + 48) / 49;
  const float w = 1.0f / (float)(e - s);
  const int c4 = threadIdx.x * 4;
  f32x4 sum = (f32x4){0.f, 0.f, 0.f, 0.f};
#pragma unroll 4
  for (int l = s; l < e; ++l) {
    const float4 v = *(const float4*)&qkv[(size_t)(bg * Nn + l) * LDQ + c4];
    sum[0] += v.x; sum[1] += v.y; sum[2] += v.z; sum[3] += v.w;
  }
  float4 o;
  o.x = sum[0] * w; o.y = sum[1] * w; o.z = sum[2] * w; o.w = sum[3] * w;
  *(float4*)&at[(size_t)(bg * Aa + a) * Cc + c4] = o;
}

// ---------------------------------------------------------------------------
// Agent attention via MFMA split-bf16. 48KB LDS, P aliases K planes,
// 3 barriers/tile (P write/read is wave-local). CHUNK=256 (64-aligned):
// chunks 0..14 run exactly 4 full j-tiles (no 1-row tail); last chunk
// absorbs row 4096. 65 tiles per (h,bg) vs 79 with CHUNK=257.
// ---------------------------------------------------------------------------
__global__ __launch_bounds__(256) void agent_attn_mfma(
    const float* __restrict__ qkv, const float* __restrict__ at,
    float* __restrict__ paccv, float* __restrict__ paccs) {
  const int chunk = blockIdx.x, h = blockIdx.y, bg = blockIdx.z;
  __shared__ __align__(16) short AhH[4096], AhL[4096];  // ah [a][d]
  __shared__ __align__(16) short KH[4096], KL[4096];    // K [j][d]; P aliases
  __shared__ __align__(16) short VtH[4096], VtL[4096];  // V^T [c][j]
  const int t = threadIdx.x;
  const int w = t >> 6, lane = t & 63, l15 = lane & 15, l4 = lane >> 4;

  for (int idx = t; idx < 512; idx += 256) {
    int a = idx >> 3, c8 = idx & 7;
    float vals[8];
    if (a < Aa) {
      const float* src = &at[(size_t)(bg * Aa + a) * Cc + h * HD + c8 * 8];
      *(float4*)&vals[0] = *(const float4*)src;
      *(float4*)&vals[4] = *(const float4*)(src + 4);
    } else {
#pragma unroll
      for (int i = 0; i < 8; ++i) vals[i] = 0.f;
    }
    s16x8 hv, lv;
#pragma unroll
    for (int i = 0; i < 8; ++i) {
      HL r = splitbf(vals[i]);
      hv[i] = r.h; lv[i] = r.l;
    }
    int pos = a * 64 + ((c8 ^ (a & 7)) << 3);
    *(s16x8*)&AhH[pos] = hv;
    *(s16x8*)&AhL[pos] = lv;
  }

  f32x4 acc[4];
#pragma unroll
  for (int ni = 0; ni < 4; ++ni) acc[ni] = (f32x4){0.f, 0.f, 0.f, 0.f};
  float rs[4] = {0.f, 0.f, 0.f, 0.f};

  const int jstart = chunk * CHUNK;
  const int jend = (chunk == NCH - 1) ? Nn : jstart + CHUNK;
  const int srow = t >> 2, sc0 = (t & 3) * 16;

  for (int j0 = jstart; j0 < jend; j0 += 64) {
    __syncthreads();   // prev tile's S (K reads) + PV (P/V reads) done
    {
      int jg = j0 + srow;
      float kv[16], vv[16];
      if (jg < jend) {
        const float* p = &qkv[(size_t)(bg * Nn + jg) * LDQ + Cc + h * HD + sc0];
#pragma unroll
        for (int r = 0; r < 4; ++r) {
          *(float4*)&kv[r * 4] = *(const float4*)(p + r * 4);
          *(float4*)&vv[r * 4] = *(const float4*)(p + Cc + r * 4);
        }
      } else {
#pragma unroll
        for (int i = 0; i < 16; ++i) { kv[i] = 0.f; vv[i] = 0.f; }
      }
#pragma unroll
      for (int r = 0; r < 2; ++r) {
        s16x8 hv, lv;
#pragma unroll
        for (int i = 0; i < 8; ++i) {
          HL s = splitbf(kv[r * 8 + i]);
          hv[i] = s.h; lv[i] = s.l;
        }
        int ch = (sc0 >> 3) + r;
        int pos = srow * 64 + ((ch ^ (srow & 7)) << 3);
        *(s16x8*)&KH[pos] = hv;
        *(s16x8*)&KL[pos] = lv;
      }
#pragma unroll
      for (int i = 0; i < 16; ++i) {
        HL s = splitbf(vv[i]);
        int c = sc0 + i;
        int pos = c * 64 + ((((srow >> 3) ^ (c & 7)) << 3)) + (srow & 7);
        VtH[pos] = s.h;
        VtL[pos] = s.l;
      }
    }
    __syncthreads();   // staged K/V visible to all waves

    f32x4 s[4];
#pragma unroll
    for (int ni = 0; ni < 4; ++ni) s[ni] = (f32x4){0.f, 0.f, 0.f, 0.f};
#pragma unroll
    for (int ks = 0; ks < 2; ++ks) {
      int sw = (((ks << 2) + l4) ^ (l15 & 7)) << 3;
      s16x8 ahh = *(const s16x8*)&AhH[(w * 16 + l15) * 64 + sw];
      s16x8 ahl = *(const s16x8*)&AhL[(w * 16 + l15) * 64 + sw];
#pragma unroll
      for (int ni = 0; ni < 4; ++ni) {
        s16x8 kh = *(const s16x8*)&KH[(ni * 16 + l15) * 64 + sw];
        s16x8 kl = *(const s16x8*)&KL[(ni * 16 + l15) * 64 + sw];
        s[ni] = __builtin_amdgcn_mfma_f32_16x16x32_bf16(ahh, kh, s[ni], 0, 0, 0);
        s[ni] = __builtin_amdgcn_mfma_f32_16x16x32_bf16(ahh, kl, s[ni], 0, 0, 0);
        s[ni] = __builtin_amdgcn_mfma_f32_16x16x32_bf16(ahl, kh, s[ni], 0, 0, 0);
      }
    }
    __syncthreads();   // all waves done reading K -> P may overwrite K planes

    // P = exp (masked); transpose-write into K planes (wave-local rows).
#pragma unroll
    for (int ni = 0; ni < 4; ++ni) {
#pragma unroll
      for (int reg = 0; reg < 4; ++reg) {
        int jj = l15 + 16 * ni;
        float pv = (j0 + jj < jend) ? expf(s[ni][reg] * SCALE) : 0.f;
        rs[reg] += pv;
        HL r = splitbf(pv);
        int a = w * 16 + l4 * 4 + reg;
        int pos = a * 64 + ((((jj >> 3) ^ (a & 7)) << 3)) + (jj & 7);
        KH[pos] = r.h;
        KL[pos] = r.l;
      }
    }

    // O += P @ V (P reads wave-local)
#pragma unroll
    for (int ks = 0; ks < 2; ++ks) {
      int sw = (((ks << 2) + l4) ^ (l15 & 7)) << 3;
      s16x8 ph = *(const s16x8*)&KH[(w * 16 + l15) * 64 + sw];
      s16x8 pl = *(const s16x8*)&KL[(w * 16 + l15) * 64 + sw];
#pragma unroll
      for (int ni = 0; ni < 4; ++ni) {
        s16x8 vh = *(const s16x8*)&VtH[(ni * 16 + l15) * 64 + sw];
        s16x8 vl = *(const s16x8*)&VtL[(ni * 16 + l15) * 64 + sw];
        acc[ni] = __builtin_amdgcn_mfma_f32_16x16x32_bf16(ph, vh, acc[ni], 0, 0, 0);
        acc[ni] = __builtin_amdgcn_mfma_f32_16x16x32_bf16(ph, vl, acc[ni], 0, 0, 0);
        acc[ni] = __builtin_amdgcn_mfma_f32_16x16x32_bf16(pl, vh, acc[ni], 0, 0, 0);
      }
    }
  }

#pragma unroll
  for (int reg = 0; reg < 4; ++reg) {
    rs[reg] += __shfl_xor(rs[reg], 1);
    rs[reg] += __shfl_xor(rs[reg], 2);
    rs[reg] += __shfl_xor(rs[reg], 4);
    rs[reg] += __shfl_xor(rs[reg], 8);
  }
  const int basev = ((bg * Hh + h) * NCH + chunk) * (Aa * 64);
#pragma unroll
  for (int reg = 0; reg < 4; ++reg) {
    int a = w * 16 + l4 * 4 + reg;
    if (a < Aa) {
#pragma unroll
      for (int ni = 0; ni < 4; ++ni)
        paccv[basev + a * 64 + l15 + 16 * ni] = acc[ni][reg];
      if (l15 == 0)
        paccs[((bg * Hh + h) * NCH + chunk) * Aa + a] = rs[reg];
    }
  }
}

// ---------------------------------------------------------------------------
// Merge chunk partials -> agent_v[bgh,a,c]
// ---------------------------------------------------------------------------
__global__ __launch_bounds__(256) void merge_agent(
    const float* __restrict__ paccv, const float* __restrict__ paccs,
    float* __restrict__ av) {
  const int bh = blockIdx.x;
  const int t = threadIdx.x;
  for (int idx = t; idx < Aa * HD; idx += 256) {
    int a = idx >> 6;
    float vs = 0.f, ss = 0.f;
#pragma unroll
    for (int ch = 0; ch < NCH; ++ch) {
      vs += paccv[(size_t)((bh * NCH + ch)) * (Aa * 64) + idx];
      ss += paccs[(bh * NCH + ch) * Aa + a];
    }
    av[(size_t)bh * (Aa * HD) + idx] = vs / ss;
  }
}

// ---------------------------------------------------------------------------
// FUSED q attention + dwc + split-pack. Vectorized epilogue: O -> LDS,
// re-gather into whole 8-channel chunks -> 16B coalesced stores.
// ---------------------------------------------------------------------------
__global__ __launch_bounds__(256) void q_attn_dwc(
    const float* __restrict__ qkv, const float* __restrict__ at,
    const float* __restrict__ av, const float* __restrict__ dwcw,
    const float* __restrict__ dwcb, short* __restrict__ Opk) {
  const int i0 = blockIdx.x * 64, h = blockIdx.y, bg = blockIdx.z;
  __shared__ __align__(16) short SMEM[24576];   // 48KB
  short* AhH = SMEM;             // [a][d] ; olds aliases after PV
  short* AhL = SMEM + 4096;
  short* AvH = SMEM + 8192;      // av^T [c][a]
  short* AvL = SMEM + 12288;
  short* QH  = SMEM + 16384;     // q [row][d]; P alias; v-stage alias
  short* QL  = SMEM + 20480;
  const int t = threadIdx.x;
  const int w = t >> 6, lane = t & 63, l15 = lane & 15, l4 = lane >> 4;

  for (int idx = t; idx < 512; idx += 256) {
    int a = idx >> 3, c8 = idx & 7;
    float vah[8], vav[8];
    if (a < Aa) {
      const float* s1 = &at[(size_t)(bg * Aa + a) * Cc + h * HD + c8 * 8];
      const float* s2 = &av[(size_t)(bg * Hh + h) * (Aa * HD) + a * HD + c8 * 8];
      *(float4*)&vah[0] = *(const float4*)s1;
      *(float4*)&vah[4] = *(const float4*)(s1 + 4);
      *(float4*)&vav[0] = *(const float4*)s2;
      *(float4*)&vav[4] = *(const float4*)(s2 + 4);
    } else {
#pragma unroll
      for (int i = 0; i < 8; ++i) { vah[i] = 0.f; vav[i] = 0.f; }
    }
    s16x8 hv, lv;
#pragma unroll
    for (int i = 0; i < 8; ++i) {
      HL r = splitbf(vah[i]);
      hv[i] = r.h; lv[i] = r.l;
    }
    int pos = a * 64 + ((c8 ^ (a & 7)) << 3);
    *(s16x8*)&AhH[pos] = hv;
    *(s16x8*)&AhL[pos] = lv;
#pragma unroll
    for (int i = 0; i < 8; ++i) {
      HL r = splitbf(vav[i]);
      int c = c8 * 8 + i;
      int pos2 = c * 64 + ((((a >> 3) ^ (c & 7)) << 3)) + (a & 7);
      AvH[pos2] = r.h;
      AvL[pos2] = r.l;
    }
  }
  {
    int row = t >> 2, c0 = (t & 3) * 16;
    int ig = i0 + row;
    float qv[16];
    if (ig < Nn) {
      const float* p = &qkv[(size_t)(bg * Nn + ig) * LDQ + h * HD + c0];
#pragma unroll
      for (int r = 0; r < 4; ++r) *(float4*)&qv[r * 4] = *(const float4*)(p + r * 4);
    } else {
#pragma unroll
      for (int i = 0; i < 16; ++i) qv[i] = 0.f;
    }
#pragma unroll
    for (int r = 0; r < 2; ++r) {
      s16x8 hv, lv;
#pragma unroll
      for (int i = 0; i < 8; ++i) {
        HL s = splitbf(qv[r * 8 + i]);
        hv[i] = s.h; lv[i] = s.l;
      }
      int ch = (c0 >> 3) + r;
      int pos = row * 64 + ((ch ^ (row & 7)) << 3);
      *(s16x8*)&QH[pos] = hv;
      *(s16x8*)&QL[pos] = lv;
    }
  }
  __syncthreads();

  // ---- S = q @ ah^T ----
  f32x4 s[4];
#pragma unroll
  for (int ni = 0; ni < 4; ++ni) s[ni] = (f32x4){0.f, 0.f, 0.f, 0.f};
#pragma unroll
  for (int ks = 0; ks < 2; ++ks) {
    int sw = (((ks << 2) + l4) ^ (l15 & 7)) << 3;
    s16x8 qh = *(const s16x8*)&QH[(w * 16 + l15) * 64 + sw];
    s16x8 ql = *(const s16x8*)&QL[(w * 16 + l15) * 64 + sw];
#pragma unroll
    for (int ni = 0; ni < 4; ++ni) {
      s16x8 bh = *(const s16x8*)&AhH[(ni * 16 + l15) * 64 + sw];
      s16x8 bl = *(const s16x8*)&AhL[(ni * 16 + l15) * 64 + sw];
      s[ni] = __builtin_amdgcn_mfma_f32_16x16x32_bf16(qh, bh, s[ni], 0, 0, 0);
      s[ni] = __builtin_amdgcn_mfma_f32_16x16x32_bf16(qh, bl, s[ni], 0, 0, 0);
      s[ni] = __builtin_amdgcn_mfma_f32_16x16x32_bf16(ql, bh, s[ni], 0, 0, 0);
    }
  }
  __syncthreads();

  // ---- softmax over agents + transpose-write P into Q planes ----
  float rsum[4] = {0.f, 0.f, 0.f, 0.f};
#pragma unroll
  for (int ni = 0; ni < 4; ++ni) {
#pragma unroll
    for (int reg = 0; reg < 4; ++reg) {
      int a = l15 + 16 * ni;
      float pv = (a < Aa) ? expf(s[ni][reg] * SCALE) : 0.f;
      s[ni][reg] = pv;
      rsum[reg] += pv;
    }
  }
#pragma unroll
  for (int reg = 0; reg < 4; ++reg) {
    rsum[reg] += __shfl_xor(rsum[reg], 1);
    rsum[reg] += __shfl_xor(rsum[reg], 2);
    rsum[reg] += __shfl_xor(rsum[reg], 4);
    rsum[reg] += __shfl_xor(rsum[reg], 8);
    rsum[reg] = 1.0f / rsum[reg];
  }
#pragma unroll
  for (int ni = 0; ni < 4; ++ni) {
#pragma unroll
    for (int reg = 0; reg < 4; ++reg) {
      HL r = splitbf(s[ni][reg] * rsum[reg]);
      int row = w * 16 + l4 * 4 + reg;
      int a = l15 + 16 * ni;
      int pos = row * 64 + ((((a >> 3) ^ (row & 7)) << 3)) + (a & 7);
      QH[pos] = r.h;
      QL[pos] = r.l;
    }
  }
  __syncthreads();

  // ---- O = P @ agent_v ----
  f32x4 o[4];
#pragma unroll
  for (int ni = 0; ni < 4; ++ni) o[ni] = (f32x4){0.f, 0.f, 0.f, 0.f};
#pragma unroll
  for (int ks = 0; ks < 2; ++ks) {
    int sw = (((ks << 2) + l4) ^ (l15 & 7)) << 3;
    s16x8 ph = *(const s16x8*)&QH[(w * 16 + l15) * 64 + sw];
    s16x8 pl = *(const s16x8*)&QL[(w * 16 + l15) * 64 + sw];
#pragma unroll
    for (int ni = 0; ni < 4; ++ni) {
      s16x8 vh = *(const s16x8*)&AvH[(ni * 16 + l15) * 64 + sw];
      s16x8 vl = *(const s16x8*)&AvL[(ni * 16 + l15) * 64 + sw];
      o[ni] = __builtin_amdgcn_mfma_f32_16x16x32_bf16(ph, vh, o[ni], 0, 0, 0);
      o[ni] = __builtin_amdgcn_mfma_f32_16x16x32_bf16(ph, vl, o[ni], 0, 0, 0);
      o[ni] = __builtin_amdgcn_mfma_f32_16x16x32_bf16(pl, vh, o[ni], 0, 0, 0);
    }
  }
  __syncthreads();  // all LDS dead -> olds / vlds may overwrite

  // ---- write O to LDS (stride 68) + stage v tile (bf16) ----
  float* olds = (float*)SMEM;                        // 64*68*4 = 17408B
  unsigned short* vlds = (unsigned short*)QH;        // 66*72*2 = 9504B
#pragma unroll
  for (int reg = 0; reg < 4; ++reg) {
    int row = w * 16 + l4 * 4 + reg;
#pragma unroll
    for (int ni = 0; ni < 4; ++ni)
      olds[row * 68 + l15 + 16 * ni] = o[ni][reg];
  }
  constexpr int VLD = 72;
  for (int idx = t; idx < 66 * 16; idx += 256) {
    int row = idx >> 4, cs = (idx & 15) << 2;
    int gr = i0 - 1 + row;
    float4 v = make_float4(0.f, 0.f, 0.f, 0.f);
    if (gr >= 0 && gr < 4096)
      v = *(const float4*)&qkv[((size_t)bg * Nn + gr) * LDQ + 2 * Cc + h * HD + cs];
    unsigned short* d = &vlds[row * VLD + cs];
    d[0] = bf16rne(v.x); d[1] = bf16rne(v.y);
    d[2] = bf16rne(v.z); d[3] = bf16rne(v.w);
  }
  __syncthreads();

  // ---- re-gather: (local row, 8-ch chunk) -> 16B stores ----
#pragma unroll
  for (int it = 0; it < 2; ++it) {
    int widx = t + it * 256;            // 0..511
    int ml = widx >> 3, kc = widx & 7;
    int ig = i0 + ml;
    if (ig >= Nn) continue;
    float vals[8];
    *(float4*)&vals[0] = *(const float4*)&olds[ml * 68 + kc * 8];
    *(float4*)&vals[4] = *(const float4*)&olds[ml * 68 + kc * 8 + 4];
    if (ig < Nn - 1) {
      const int rl = ml + 1;
      const unsigned short* vr = &vlds[rl * VLD + kc * 8];
#pragma unroll
      for (int cI = 0; cI < 8; ++cI) {
        int cg = h * HD + kc * 8 + cI;
        float vm = bf2f(vr[cI - VLD]);
        float v0 = bf2f(vr[cI]);
        float vp = bf2f(vr[cI + VLD]);
        vals[cI] += dwcw[cg * 3] * vm + dwcw[cg * 3 + 1] * v0 +
                    dwcw[cg * 3 + 2] * vp + dwcb[cg];
      }
    }
    s16x8 hv, lv;
#pragma unroll
    for (int cI = 0; cI < 8; ++cI) {
      HL r = splitbf(vals[cI]);
      hv[cI] = r.h; lv[cI] = r.l;
    }
    const int mrow = bg * Nn + ig;
    const int win = h * 64;                        // (kcg>>3)*64, kcg=h*8+kc
    const int jj = (kc ^ (mrow & 7)) * 8;
    *(s16x8*)&Opk[(size_t)mrow * KP + win + jj] = hv;
    *(s16x8*)&Opk[(size_t)mrow * KP + 768 + win + jj] = lv;
  }
}

}  // namespace

extern "C" void kernel_launch(void* const* d_in, const int* in_sizes, int n_in,
                              void* d_out, int out_size, void* d_ws,
                              size_t ws_size, hipStream_t stream) {
  const float* x = (const float*)d_in[0];
  const float* Wqkv = (const float*)d_in[1];
  const float* Wproj = (const float*)d_in[2];
  const float* bproj = (const float*)d_in[3];
  const float* dwcw = (const float*)d_in[4];
  const float* dwcb = (const float*)d_in[5];
  float* out = (float*)d_out;

  // --- fixed workspace: packed weight planes ---
  char* p = (char*)d_ws;
  short* WQpk = (short*)p; p += (size_t)LDQ * KP * 2;   // 7,077,888 B
  short* WPpk = (short*)p; p += (size_t)Cc * KP * 2;    // 2,359,296 B
  const size_t fixedBytes = (size_t)p - (size_t)d_ws;

  auto bytesFor = [&](int G) -> size_t {
    size_t Mg = (size_t)G * Nn;
    size_t Mpad = ((Mg + 127) / 128) * 128;
    size_t fl = Mg * LDQ +
                (size_t)G * (Aa * Cc + Hh * NCH * Aa * 64 + Hh * NCH * Aa +
                             Hh * Aa * HD);
    return fixedBytes + fl * 4 + Mpad * KP * 2;            // + Apk/Opk
  };
  int G = 1;
  for (int g = Bb; g >= 1; --g) {
    if (bytesFor(g) <= ws_size) { G = g; break; }
  }

  const size_t MgMax = (size_t)G * Nn;
  float* qkv = (float*)p;
  float* at = qkv + MgMax * LDQ;
  float* paccv = at + (size_t)G * Aa * Cc;
  float* paccs = paccv + (size_t)G * Hh * NCH * Aa * 64;
  float* av = paccs + (size_t)G * Hh * NCH * Aa;
  short* Apk = (short*)(av + (size_t)G * Hh * Aa * HD);   // aliased as Opk

  dim3 blk(256);
  // 0) pack weights (once per launch; deterministic)
  pack_w<<<dim3((96 * LDQ + 255) / 256), blk, 0, stream>>>(Wqkv, WQpk, LDQ);
  pack_w<<<dim3((96 * Cc + 255) / 256), blk, 0, stream>>>(Wproj, WPpk, Cc);

  for (int b0 = 0; b0 < Bb; b0 += G) {
    const int Gi = (b0 + G <= Bb) ? G : (Bb - b0);
    const int Mg = Gi * Nn;
    const int Mtiles = (Mg + 127) / 128;
    const float* xg = x + (size_t)b0 * Nn * Cc;
    float* outg = out + (size_t)b0 * Nn * Cc;

    // 1) pack x -> Apk, then qkv = x @ Wqkv (tiered: q,k 2-product; v full)
    pack_act<<<dim3((Mg * 96 + 255) / 256), blk, 0, stream>>>(xg, Apk, Mg);
    {
      const int nch = LDQ / 128;            // 18
      const int nwg = Mtiles * nch;
      gemm_pk2<<<dim3(nwg), blk, 0, stream>>>(Apk, WQpk, qkv, nullptr, Mg,
                                              LDQ, nch, nwg, 2 * Cc);
    }
    // 2) agent tokens (adaptive pool of q)
    pool_agents<<<dim3(Gi * Aa), dim3(192), 0, stream>>>(qkv, at);
    // 3) agent attention partials (MFMA) + merge -> agent_v
    agent_attn_mfma<<<dim3(NCH, Hh, Gi), blk, 0, stream>>>(qkv, at, paccv,
                                                           paccs);
    merge_agent<<<dim3(Gi * Hh), blk, 0, stream>>>(paccv, paccs, av);
    // 4) fused q attention + dwc + pack -> Opk(=Apk)
    q_attn_dwc<<<dim3((Nn + 63) / 64, Hh, Gi), blk, 0, stream>>>(
        qkv, at, av, dwcw, dwcb, Apk);
    // 5) final projection -> out_g (+bias; full split everywhere)
    {
      const int nch = Cc / 128;             // 6
      const int nwg = Mtiles * nch;
      gemm_pk2<<<dim3(nwg), blk, 0, stream>>>(Apk, WPpk, outg, bproj, Mg,
                                              Cc, nch, nwg, 0);
    }
  }
}

// Round 16
// 610.202 us; speedup vs baseline: 1.4533x; 1.2496x over previous
//
#include <hip/hip_runtime.h>

namespace {

constexpr int Bb = 8;
constexpr int Nn = 4097;
constexpr int Cc = 768;
constexpr int Hh = 12;
constexpr int HD = 64;
constexpr int Aa = 49;
constexpr int LDQ = 3 * Cc;        // 2304 (qkv row stride)
constexpr int NCH = 16;            // j-chunks for agent attention
constexpr int CHUNK = 256;         // 64-aligned; last chunk absorbs row 4096
constexpr float SCALE = 0.125f;    // hd^-0.5
constexpr int KP = 1536;           // WEIGHT packed row length (hi 768|lo 768)
constexpr int KA = 768;            // ACTIVATION packed row length (RNE bf16)

typedef short s16x8 __attribute__((ext_vector_type(8)));
typedef float f32x4 __attribute__((ext_vector_type(4)));

struct HL { short h, l; };

// Split fp32 into hi (truncated bf16, exact bits) + lo (RNE bf16 of residual).
__device__ inline HL splitbf(float v) {
  unsigned u = __float_as_uint(v);
  HL r;
  r.h = (short)(u >> 16);
  float hf = __uint_as_float(u & 0xffff0000u);
  float lf = v - hf;
  unsigned ul = __float_as_uint(lf);
  r.l = (short)((ul + 0x7fffu + ((ul >> 16) & 1u)) >> 16);
  return r;
}

__device__ inline short bf16rne(float v) {
  unsigned u = __float_as_uint(v);
  return (short)((u + 0x7fffu + ((u >> 16) & 1u)) >> 16);
}
__device__ inline float bf2f(unsigned short s) {
  return __uint_as_float((unsigned)s << 16);
}

// async global->LDS, 16B per lane (linear dest)
__device__ inline void gload16(const short* g, void* l) {
  __builtin_amdgcn_global_load_lds(
      (const __attribute__((address_space(1))) void*)g,
      (__attribute__((address_space(3))) void*)l, 16, 0, 0);
}

// Packed layout: per row, 12 windows of 64 elems (8 chunks of 8);
// physical chunk = logical chunk ^ (row&7).
// Weights: [N][1536] = [hi | lo] split. Activations: [M][768] single RNE.

// ---------------------------------------------------------------------------
// Pack activations: src[M][768] fp32 -> dst[M][768] RNE bf16.
// ---------------------------------------------------------------------------
__global__ __launch_bounds__(256) void pack_act(
    const float* __restrict__ src, short* __restrict__ dst, int M) {
  int idx = blockIdx.x * 256 + threadIdx.x;
  if (idx >= M * 96) return;
  int m = idx / 96, kc = idx - m * 96;
  const float* s = src + (size_t)m * 768 + kc * 8;
  float4 v0 = *(const float4*)s;
  float4 v1 = *(const float4*)(s + 4);
  s16x8 hv;
  hv[0] = bf16rne(v0.x); hv[1] = bf16rne(v0.y);
  hv[2] = bf16rne(v0.z); hv[3] = bf16rne(v0.w);
  hv[4] = bf16rne(v1.x); hv[5] = bf16rne(v1.y);
  hv[6] = bf16rne(v1.z); hv[7] = bf16rne(v1.w);
  int win = (kc >> 3) * 64;
  int jj = ((kc & 7) ^ (m & 7)) * 8;
  *(s16x8*)&dst[(size_t)m * KA + win + jj] = hv;
}

// ---------------------------------------------------------------------------
// Pack weights: W[768][N] fp32 -> Wpk[N][1536] bf16 split, key (n&7).
// ---------------------------------------------------------------------------
__global__ __launch_bounds__(256) void pack_w(
    const float* __restrict__ W, short* __restrict__ Wpk, int N) {
  int idx = blockIdx.x * 256 + threadIdx.x;
  if (idx >= 96 * N) return;
  int kc = idx / N, n = idx - kc * N;
  s16x8 hv, lv;
#pragma unroll
  for (int i = 0; i < 8; ++i) {
    HL r = splitbf(W[(size_t)(kc * 8 + i) * N + n]);
    hv[i] = r.h; lv[i] = r.l;
  }
  int win = (kc >> 3) * 64;
  int jj = ((kc & 7) ^ (n & 7)) * 8;
  short* d = Wpk + (size_t)n * KP;
  *(s16x8*)&d[win + jj] = hv;
  *(s16x8*)&d[768 + win + jj] = lv;
}

// ---------------------------------------------------------------------------
// C[M x N] = A @ B (+bias): A = RNE bf16 [M][768], B = split [N][1536].
// 2 products (a*bh + a*bl) -> 64 MFMA per kt, 3 staged planes (48KB LDS,
// 3 blocks/CU). R12 barrier structure (frozen). 12 kt iterations.
// ---------------------------------------------------------------------------
__global__ __launch_bounds__(256) void gemm_pk2(
    const short* __restrict__ Apk, const short* __restrict__ Bpk,
    float* __restrict__ Cm, const float* __restrict__ bias,
    int Mr, int ldc, int nch, int nwg) {
  __shared__ __align__(16) short AsH[128 * 64];
  __shared__ __align__(16) short BsH[128 * 64], BsL[128 * 64];
  const int t = threadIdx.x;
  const int lane = t & 63;
  const int w = t >> 6;
  const int wr = w >> 1, wc = w & 1;
  const int l15 = lane & 15, l4 = lane >> 4;

  const int j = blockIdx.x;
  const int q = nwg >> 3, r = nwg & 7;
  const int xcd = j & 7, pos = j >> 3;
  const int logical =
      (xcd < r ? xcd * (q + 1) : r * (q + 1) + (xcd - r) * q) + pos;
  const int mt = logical / nch, nc = logical - mt * nch;
  const int m0 = mt * 128, n0 = nc * 128;

  f32x4 acc[4][4];
#pragma unroll
  for (int mi = 0; mi < 4; ++mi)
#pragma unroll
    for (int ni = 0; ni < 4; ++ni) acc[mi][ni] = (f32x4){0.f, 0.f, 0.f, 0.f};

  for (int kt = 0; kt < 12; ++kt) {
    const short* Ab = Apk + (size_t)m0 * KA + kt * 64;
    const short* Bt = Bpk + (size_t)n0 * KP + kt * 64;
    __syncthreads();
#pragma unroll
    for (int i = 0; i < 4; ++i) {
      const int o = (i * 256 + t) * 16;   // byte offset in 16KB plane
      const int row = o >> 7;
      const int ce = (o & 127) >> 1;      // element col (physical)
      gload16(Ab + (size_t)row * KA + ce, (char*)AsH + o);
      gload16(Bt + (size_t)row * KP + ce, (char*)BsH + o);
      gload16(Bt + (size_t)row * KP + 768 + ce, (char*)BsL + o);
    }
    __syncthreads();
#pragma unroll
    for (int ks = 0; ks < 2; ++ks) {
      s16x8 ah[4], bh[4], bl[4];
#pragma unroll
      for (int mi = 0; mi < 4; ++mi) {
        int rr = wr * 64 + mi * 16 + l15;
        ah[mi] = *(const s16x8*)&AsH[rr * 64 + ((((ks << 2) + l4) ^ (l15 & 7)) << 3)];
      }
#pragma unroll
      for (int ni = 0; ni < 4; ++ni) {
        int rr = wc * 64 + ni * 16 + l15;
        int off = rr * 64 + ((((ks << 2) + l4) ^ (l15 & 7)) << 3);
        bh[ni] = *(const s16x8*)&BsH[off];
        bl[ni] = *(const s16x8*)&BsL[off];
      }
#pragma unroll
      for (int mi = 0; mi < 4; ++mi)
#pragma unroll
        for (int ni = 0; ni < 4; ++ni) {
          acc[mi][ni] = __builtin_amdgcn_mfma_f32_16x16x32_bf16(
              ah[mi], bh[ni], acc[mi][ni], 0, 0, 0);
          acc[mi][ni] = __builtin_amdgcn_mfma_f32_16x16x32_bf16(
              ah[mi], bl[ni], acc[mi][ni], 0, 0, 0);
        }
    }
  }

#pragma unroll
  for (int mi = 0; mi < 4; ++mi) {
#pragma unroll
    for (int jr = 0; jr < 4; ++jr) {
      int gr = m0 + wr * 64 + mi * 16 + l4 * 4 + jr;
      if (gr < Mr) {
#pragma unroll
        for (int ni = 0; ni < 4; ++ni) {
          int gc = n0 + wc * 64 + ni * 16 + l15;
          float v = acc[mi][ni][jr];
          if (bias) v += bias[gc];
          Cm[(size_t)gr * ldc + gc] = v;
        }
      }
    }
  }
}

// ---------------------------------------------------------------------------
// Adaptive-pool agents: at[bg,a,c] = mean over q rows [s,e) of q[bg,l,c].
// ---------------------------------------------------------------------------
__global__ __launch_bounds__(192) void pool_agents(
    const float* __restrict__ qkv, float* __restrict__ at) {
  const int ba = blockIdx.x;
  const int bg = ba / Aa, a = ba % Aa;
  const int s = (a * 4096) / 49;
  const int e = ((a + 1) * 4096 + 48) / 49;
  const float w = 1.0f / (float)(e - s);
  const int c4 = threadIdx.x * 4;
  f32x4 sum = (f32x4){0.f, 0.f, 0.f, 0.f};
#pragma unroll 4
  for (int l = s; l < e; ++l) {
    const float4 v = *(const float4*)&qkv[(size_t)(bg * Nn + l) * LDQ + c4];
    sum[0] += v.x; sum[1] += v.y; sum[2] += v.z; sum[3] += v.w;
  }
  float4 o;
  o.x = sum[0] * w; o.y = sum[1] * w; o.z = sum[2] * w; o.w = sum[3] * w;
  *(float4*)&at[(size_t)(bg * Aa + a) * Cc + c4] = o;
}

// ---------------------------------------------------------------------------
// Agent attention: ah/P single RNE plane (A-operands), K/V split (B).
// S: 2 MFMA, PV: 2 MFMA. 40KB LDS -> 4 blocks/CU. 3 barriers/tile.
// ---------------------------------------------------------------------------
__global__ __launch_bounds__(256) void agent_attn_mfma(
    const float* __restrict__ qkv, const float* __restrict__ at,
    float* __restrict__ paccv, float* __restrict__ paccs) {
  const int chunk = blockIdx.x, h = blockIdx.y, bg = blockIdx.z;
  __shared__ __align__(16) short AhH[4096];             // ah [a][d], RNE
  __shared__ __align__(16) short KH[4096], KL[4096];    // K split; P -> KH
  __shared__ __align__(16) short VtH[4096], VtL[4096];  // V^T split
  const int t = threadIdx.x;
  const int w = t >> 6, lane = t & 63, l15 = lane & 15, l4 = lane >> 4;

  for (int idx = t; idx < 512; idx += 256) {
    int a = idx >> 3, c8 = idx & 7;
    float vals[8];
    if (a < Aa) {
      const float* src = &at[(size_t)(bg * Aa + a) * Cc + h * HD + c8 * 8];
      *(float4*)&vals[0] = *(const float4*)src;
      *(float4*)&vals[4] = *(const float4*)(src + 4);
    } else {
#pragma unroll
      for (int i = 0; i < 8; ++i) vals[i] = 0.f;
    }
    s16x8 hv;
#pragma unroll
    for (int i = 0; i < 8; ++i) hv[i] = bf16rne(vals[i]);
    *(s16x8*)&AhH[a * 64 + ((c8 ^ (a & 7)) << 3)] = hv;
  }

  f32x4 acc[4];
#pragma unroll
  for (int ni = 0; ni < 4; ++ni) acc[ni] = (f32x4){0.f, 0.f, 0.f, 0.f};
  float rs[4] = {0.f, 0.f, 0.f, 0.f};

  const int jstart = chunk * CHUNK;
  const int jend = (chunk == NCH - 1) ? Nn : jstart + CHUNK;
  const int srow = t >> 2, sc0 = (t & 3) * 16;

  for (int j0 = jstart; j0 < jend; j0 += 64) {
    __syncthreads();   // prev tile's S/PV reads done
    {
      int jg = j0 + srow;
      float kv[16], vv[16];
      if (jg < jend) {
        const float* p = &qkv[(size_t)(bg * Nn + jg) * LDQ + Cc + h * HD + sc0];
#pragma unroll
        for (int r = 0; r < 4; ++r) {
          *(float4*)&kv[r * 4] = *(const float4*)(p + r * 4);
          *(float4*)&vv[r * 4] = *(const float4*)(p + Cc + r * 4);
        }
      } else {
#pragma unroll
        for (int i = 0; i < 16; ++i) { kv[i] = 0.f; vv[i] = 0.f; }
      }
#pragma unroll
      for (int r = 0; r < 2; ++r) {
        s16x8 hv, lv;
#pragma unroll
        for (int i = 0; i < 8; ++i) {
          HL s = splitbf(kv[r * 8 + i]);
          hv[i] = s.h; lv[i] = s.l;
        }
        int ch = (sc0 >> 3) + r;
        int pos = srow * 64 + ((ch ^ (srow & 7)) << 3);
        *(s16x8*)&KH[pos] = hv;
        *(s16x8*)&KL[pos] = lv;
      }
#pragma unroll
      for (int i = 0; i < 16; ++i) {
        HL s = splitbf(vv[i]);
        int c = sc0 + i;
        int pos = c * 64 + ((((srow >> 3) ^ (c & 7)) << 3)) + (srow & 7);
        VtH[pos] = s.h;
        VtL[pos] = s.l;
      }
    }
    __syncthreads();   // staged K/V visible

    f32x4 s[4];
#pragma unroll
    for (int ni = 0; ni < 4; ++ni) s[ni] = (f32x4){0.f, 0.f, 0.f, 0.f};
#pragma unroll
    for (int ks = 0; ks < 2; ++ks) {
      int sw = (((ks << 2) + l4) ^ (l15 & 7)) << 3;
      s16x8 ahh = *(const s16x8*)&AhH[(w * 16 + l15) * 64 + sw];
#pragma unroll
      for (int ni = 0; ni < 4; ++ni) {
        s16x8 kh = *(const s16x8*)&KH[(ni * 16 + l15) * 64 + sw];
        s16x8 kl = *(const s16x8*)&KL[(ni * 16 + l15) * 64 + sw];
        s[ni] = __builtin_amdgcn_mfma_f32_16x16x32_bf16(ahh, kh, s[ni], 0, 0, 0);
        s[ni] = __builtin_amdgcn_mfma_f32_16x16x32_bf16(ahh, kl, s[ni], 0, 0, 0);
      }
    }
    __syncthreads();   // all waves done reading K -> P may overwrite KH

    // P = exp (masked), RNE; transpose-write into KH (wave-local rows).
#pragma unroll
    for (int ni = 0; ni < 4; ++ni) {
#pragma unroll
      for (int reg = 0; reg < 4; ++reg) {
        int jj = l15 + 16 * ni;
        float pv = (j0 + jj < jend) ? expf(s[ni][reg] * SCALE) : 0.f;
        rs[reg] += pv;
        int a = w * 16 + l4 * 4 + reg;
        KH[a * 64 + ((((jj >> 3) ^ (a & 7)) << 3)) + (jj & 7)] = bf16rne(pv);
      }
    }

    // O += P @ V (P reads wave-local)
#pragma unroll
    for (int ks = 0; ks < 2; ++ks) {
      int sw = (((ks << 2) + l4) ^ (l15 & 7)) << 3;
      s16x8 ph = *(const s16x8*)&KH[(w * 16 + l15) * 64 + sw];
#pragma unroll
      for (int ni = 0; ni < 4; ++ni) {
        s16x8 vh = *(const s16x8*)&VtH[(ni * 16 + l15) * 64 + sw];
        s16x8 vl = *(const s16x8*)&VtL[(ni * 16 + l15) * 64 + sw];
        acc[ni] = __builtin_amdgcn_mfma_f32_16x16x32_bf16(ph, vh, acc[ni], 0, 0, 0);
        acc[ni] = __builtin_amdgcn_mfma_f32_16x16x32_bf16(ph, vl, acc[ni], 0, 0, 0);
      }
    }
  }

#pragma unroll
  for (int reg = 0; reg < 4; ++reg) {
    rs[reg] += __shfl_xor(rs[reg], 1);
    rs[reg] += __shfl_xor(rs[reg], 2);
    rs[reg] += __shfl_xor(rs[reg], 4);
    rs[reg] += __shfl_xor(rs[reg], 8);
  }
  const int basev = ((bg * Hh + h) * NCH + chunk) * (Aa * 64);
#pragma unroll
  for (int reg = 0; reg < 4; ++reg) {
    int a = w * 16 + l4 * 4 + reg;
    if (a < Aa) {
#pragma unroll
      for (int ni = 0; ni < 4; ++ni)
        paccv[basev + a * 64 + l15 + 16 * ni] = acc[ni][reg];
      if (l15 == 0)
        paccs[((bg * Hh + h) * NCH + chunk) * Aa + a] = rs[reg];
    }
  }
}

// ---------------------------------------------------------------------------
// Merge chunk partials -> agent_v[bgh,a,c]
// ---------------------------------------------------------------------------
__global__ __launch_bounds__(256) void merge_agent(
    const float* __restrict__ paccv, const float* __restrict__ paccs,
    float* __restrict__ av) {
  const int bh = blockIdx.x;
  const int t = threadIdx.x;
  for (int idx = t; idx < Aa * HD; idx += 256) {
    int a = idx >> 6;
    float vs = 0.f, ss = 0.f;
#pragma unroll
    for (int ch = 0; ch < NCH; ++ch) {
      vs += paccv[(size_t)((bh * NCH + ch)) * (Aa * 64) + idx];
      ss += paccs[(bh * NCH + ch) * Aa + a];
    }
    av[(size_t)bh * (Aa * HD) + idx] = vs / ss;
  }
}

// ---------------------------------------------------------------------------
// FUSED q attention + dwc + pack. q/P single RNE plane; ah/av split.
// 40KB LDS. Epilogue: O->LDS, re-gather, 16B stores to Opk (stride 768).
// ---------------------------------------------------------------------------
__global__ __launch_bounds__(256) void q_attn_dwc(
    const float* __restrict__ qkv, const float* __restrict__ at,
    const float* __restrict__ av, const float* __restrict__ dwcw,
    const float* __restrict__ dwcb, short* __restrict__ Opk) {
  const int i0 = blockIdx.x * 64, h = blockIdx.y, bg = blockIdx.z;
  __shared__ __align__(16) short SMEM[20480];   // 40KB
  short* AhH = SMEM;             // ah split (B-operand)
  short* AhL = SMEM + 4096;
  short* AvH = SMEM + 8192;      // av^T split (B-operand)
  short* AvL = SMEM + 12288;
  short* QH  = SMEM + 16384;     // q RNE (A); P alias
  const int t = threadIdx.x;
  const int w = t >> 6, lane = t & 63, l15 = lane & 15, l4 = lane >> 4;

  for (int idx = t; idx < 512; idx += 256) {
    int a = idx >> 3, c8 = idx & 7;
    float vah[8], vav[8];
    if (a < Aa) {
      const float* s1 = &at[(size_t)(bg * Aa + a) * Cc + h * HD + c8 * 8];
      const float* s2 = &av[(size_t)(bg * Hh + h) * (Aa * HD) + a * HD + c8 * 8];
      *(float4*)&vah[0] = *(const float4*)s1;
      *(float4*)&vah[4] = *(const float4*)(s1 + 4);
      *(float4*)&vav[0] = *(const float4*)s2;
      *(float4*)&vav[4] = *(const float4*)(s2 + 4);
    } else {
#pragma unroll
      for (int i = 0; i < 8; ++i) { vah[i] = 0.f; vav[i] = 0.f; }
    }
    s16x8 hv, lv;
#pragma unroll
    for (int i = 0; i < 8; ++i) {
      HL r = splitbf(vah[i]);
      hv[i] = r.h; lv[i] = r.l;
    }
    int pos = a * 64 + ((c8 ^ (a & 7)) << 3);
    *(s16x8*)&AhH[pos] = hv;
    *(s16x8*)&AhL[pos] = lv;
#pragma unroll
    for (int i = 0; i < 8; ++i) {
      HL r = splitbf(vav[i]);
      int c = c8 * 8 + i;
      int pos2 = c * 64 + ((((a >> 3) ^ (c & 7)) << 3)) + (a & 7);
      AvH[pos2] = r.h;
      AvL[pos2] = r.l;
    }
  }
  {
    int row = t >> 2, c0 = (t & 3) * 16;
    int ig = i0 + row;
    float qv[16];
    if (ig < Nn) {
      const float* p = &qkv[(size_t)(bg * Nn + ig) * LDQ + h * HD + c0];
#pragma unroll
      for (int r = 0; r < 4; ++r) *(float4*)&qv[r * 4] = *(const float4*)(p + r * 4);
    } else {
#pragma unroll
      for (int i = 0; i < 16; ++i) qv[i] = 0.f;
    }
#pragma unroll
    for (int r = 0; r < 2; ++r) {
      s16x8 hv;
#pragma unroll
      for (int i = 0; i < 8; ++i) hv[i] = bf16rne(qv[r * 8 + i]);
      int ch = (c0 >> 3) + r;
      *(s16x8*)&QH[row * 64 + ((ch ^ (row & 7)) << 3)] = hv;
    }
  }
  __syncthreads();

  // ---- S = q @ ah^T (2 products) ----
  f32x4 s[4];
#pragma unroll
  for (int ni = 0; ni < 4; ++ni) s[ni] = (f32x4){0.f, 0.f, 0.f, 0.f};
#pragma unroll
  for (int ks = 0; ks < 2; ++ks) {
    int sw = (((ks << 2) + l4) ^ (l15 & 7)) << 3;
    s16x8 qh = *(const s16x8*)&QH[(w * 16 + l15) * 64 + sw];
#pragma unroll
    for (int ni = 0; ni < 4; ++ni) {
      s16x8 bh = *(const s16x8*)&AhH[(ni * 16 + l15) * 64 + sw];
      s16x8 bl = *(const s16x8*)&AhL[(ni * 16 + l15) * 64 + sw];
      s[ni] = __builtin_amdgcn_mfma_f32_16x16x32_bf16(qh, bh, s[ni], 0, 0, 0);
      s[ni] = __builtin_amdgcn_mfma_f32_16x16x32_bf16(qh, bl, s[ni], 0, 0, 0);
    }
  }
  __syncthreads();  // all waves done reading Q -> P may overwrite

  // ---- softmax over agents + transpose-write P (RNE) into QH ----
  float rsum[4] = {0.f, 0.f, 0.f, 0.f};
#pragma unroll
  for (int ni = 0; ni < 4; ++ni) {
#pragma unroll
    for (int reg = 0; reg < 4; ++reg) {
      int a = l15 + 16 * ni;
      float pv = (a < Aa) ? expf(s[ni][reg] * SCALE) : 0.f;
      s[ni][reg] = pv;
      rsum[reg] += pv;
    }
  }
#pragma unroll
  for (int reg = 0; reg < 4; ++reg) {
    rsum[reg] += __shfl_xor(rsum[reg], 1);
    rsum[reg] += __shfl_xor(rsum[reg], 2);
    rsum[reg] += __shfl_xor(rsum[reg], 4);
    rsum[reg] += __shfl_xor(rsum[reg], 8);
    rsum[reg] = 1.0f / rsum[reg];
  }
#pragma unroll
  for (int ni = 0; ni < 4; ++ni) {
#pragma unroll
    for (int reg = 0; reg < 4; ++reg) {
      int row = w * 16 + l4 * 4 + reg;
      int a = l15 + 16 * ni;
      QH[row * 64 + ((((a >> 3) ^ (row & 7)) << 3)) + (a & 7)] =
          bf16rne(s[ni][reg] * rsum[reg]);
    }
  }
  __syncthreads();

  // ---- O = P @ agent_v (2 products) ----
  f32x4 o[4];
#pragma unroll
  for (int ni = 0; ni < 4; ++ni) o[ni] = (f32x4){0.f, 0.f, 0.f, 0.f};
#pragma unroll
  for (int ks = 0; ks < 2; ++ks) {
    int sw = (((ks << 2) + l4) ^ (l15 & 7)) << 3;
    s16x8 ph = *(const s16x8*)&QH[(w * 16 + l15) * 64 + sw];
#pragma unroll
    for (int ni = 0; ni < 4; ++ni) {
      s16x8 vh = *(const s16x8*)&AvH[(ni * 16 + l15) * 64 + sw];
      s16x8 vl = *(const s16x8*)&AvL[(ni * 16 + l15) * 64 + sw];
      o[ni] = __builtin_amdgcn_mfma_f32_16x16x32_bf16(ph, vh, o[ni], 0, 0, 0);
      o[ni] = __builtin_amdgcn_mfma_f32_16x16x32_bf16(ph, vl, o[ni], 0, 0, 0);
    }
  }
  __syncthreads();  // all LDS dead -> olds / vlds may overwrite

  // ---- write O to LDS (stride 68) + stage v tile (bf16) ----
  float* olds = (float*)SMEM;                         // 17408B
  unsigned short* vlds = (unsigned short*)(SMEM + 9216);  // 9504B, disjoint
#pragma unroll
  for (int reg = 0; reg < 4; ++reg) {
    int row = w * 16 + l4 * 4 + reg;
#pragma unroll
    for (int ni = 0; ni < 4; ++ni)
      olds[row * 68 + l15 + 16 * ni] = o[ni][reg];
  }
  constexpr int VLD = 72;
  for (int idx = t; idx < 66 * 16; idx += 256) {
    int row = idx >> 4, cs = (idx & 15) << 2;
    int gr = i0 - 1 + row;
    float4 v = make_float4(0.f, 0.f, 0.f, 0.f);
    if (gr >= 0 && gr < 4096)
      v = *(const float4*)&qkv[((size_t)bg * Nn + gr) * LDQ + 2 * Cc + h * HD + cs];
    unsigned short* d = &vlds[row * VLD + cs];
    d[0] = (unsigned short)bf16rne(v.x); d[1] = (unsigned short)bf16rne(v.y);
    d[2] = (unsigned short)bf16rne(v.z); d[3] = (unsigned short)bf16rne(v.w);
  }
  __syncthreads();

  // ---- re-gather: (local row, 8-ch chunk) -> one 16B store ----
#pragma unroll
  for (int it = 0; it < 2; ++it) {
    int widx = t + it * 256;            // 0..511
    int ml = widx >> 3, kc = widx & 7;
    int ig = i0 + ml;
    if (ig >= Nn) continue;
    float vals[8];
    *(float4*)&vals[0] = *(const float4*)&olds[ml * 68 + kc * 8];
    *(float4*)&vals[4] = *(const float4*)&olds[ml * 68 + kc * 8 + 4];
    if (ig < Nn - 1) {
      const int rl = ml + 1;
      const unsigned short* vr = &vlds[rl * VLD + kc * 8];
#pragma unroll
      for (int cI = 0; cI < 8; ++cI) {
        int cg = h * HD + kc * 8 + cI;
        float vm = bf2f(vr[cI - VLD]);
        float v0 = bf2f(vr[cI]);
        float vp = bf2f(vr[cI + VLD]);
        vals[cI] += dwcw[cg * 3] * vm + dwcw[cg * 3 + 1] * v0 +
                    dwcw[cg * 3 + 2] * vp + dwcb[cg];
      }
    }
    s16x8 hv;
#pragma unroll
    for (int cI = 0; cI < 8; ++cI) hv[cI] = bf16rne(vals[cI]);
    const int mrow = bg * Nn + ig;
    const int win = h * 64;
    const int jj = (kc ^ (mrow & 7)) * 8;
    *(s16x8*)&Opk[(size_t)mrow * KA + win + jj] = hv;
  }
}

}  // namespace

extern "C" void kernel_launch(void* const* d_in, const int* in_sizes, int n_in,
                              void* d_out, int out_size, void* d_ws,
                              size_t ws_size, hipStream_t stream) {
  const float* x = (const float*)d_in[0];
  const float* Wqkv = (const float*)d_in[1];
  const float* Wproj = (const float*)d_in[2];
  const float* bproj = (const float*)d_in[3];
  const float* dwcw = (const float*)d_in[4];
  const float* dwcb = (const float*)d_in[5];
  float* out = (float*)d_out;

  // --- fixed workspace: packed weight planes ---
  char* p = (char*)d_ws;
  short* WQpk = (short*)p; p += (size_t)LDQ * KP * 2;   // 7,077,888 B
  short* WPpk = (short*)p; p += (size_t)Cc * KP * 2;    // 2,359,296 B
  const size_t fixedBytes = (size_t)p - (size_t)d_ws;

  auto bytesFor = [&](int G) -> size_t {
    size_t Mg = (size_t)G * Nn;
    size_t Mpad = ((Mg + 127) / 128) * 128;
    size_t fl = Mg * LDQ +
                (size_t)G * (Aa * Cc + Hh * NCH * Aa * 64 + Hh * NCH * Aa +
                             Hh * Aa * HD);
    return fixedBytes + fl * 4 + Mpad * KA * 2;            // + Apk/Opk (RNE)
  };
  int G = 1;
  for (int g = Bb; g >= 1; --g) {
    if (bytesFor(g) <= ws_size) { G = g; break; }
  }

  const size_t MgMax = (size_t)G * Nn;
  float* qkv = (float*)p;
  float* at = qkv + MgMax * LDQ;
  float* paccv = at + (size_t)G * Aa * Cc;
  float* paccs = paccv + (size_t)G * Hh * NCH * Aa * 64;
  float* av = paccs + (size_t)G * Hh * NCH * Aa;
  short* Apk = (short*)(av + (size_t)G * Hh * Aa * HD);   // aliased as Opk

  dim3 blk(256);
  // 0) pack weights (once per launch; deterministic)
  pack_w<<<dim3((96 * LDQ + 255) / 256), blk, 0, stream>>>(Wqkv, WQpk, LDQ);
  pack_w<<<dim3((96 * Cc + 255) / 256), blk, 0, stream>>>(Wproj, WPpk, Cc);

  for (int b0 = 0; b0 < Bb; b0 += G) {
    const int Gi = (b0 + G <= Bb) ? G : (Bb - b0);
    const int Mg = Gi * Nn;
    const int Mtiles = (Mg + 127) / 128;
    const float* xg = x + (size_t)b0 * Nn * Cc;
    float* outg = out + (size_t)b0 * Nn * Cc;

    // 1) pack x (RNE) -> Apk, then qkv = x @ Wqkv
    pack_act<<<dim3((Mg * 96 + 255) / 256), blk, 0, stream>>>(xg, Apk, Mg);
    {
      const int nch = LDQ / 128;            // 18
      const int nwg = Mtiles * nch;
      gemm_pk2<<<dim3(nwg), blk, 0, stream>>>(Apk, WQpk, qkv, nullptr, Mg,
                                              LDQ, nch, nwg);
    }
    // 2) agent tokens (adaptive pool of q)
    pool_agents<<<dim3(Gi * Aa), dim3(192), 0, stream>>>(qkv, at);
    // 3) agent attention partials (MFMA) + merge -> agent_v
    agent_attn_mfma<<<dim3(NCH, Hh, Gi), blk, 0, stream>>>(qkv, at, paccv,
                                                           paccs);
    merge_agent<<<dim3(Gi * Hh), blk, 0, stream>>>(paccv, paccs, av);
    // 4) fused q attention + dwc + pack (RNE) -> Opk(=Apk)
    q_attn_dwc<<<dim3((Nn + 63) / 64, Hh, Gi), blk, 0, stream>>>(
        qkv, at, av, dwcw, dwcb, Apk);
    // 5) final projection -> out_g (+bias)
    {
      const int nch = Cc / 128;             // 6
      const int nwg = Mtiles * nch;
      gemm_pk2<<<dim3(nwg), blk, 0, stream>>>(Apk, WPpk, outg, bproj, Mg,
                                              Cc, nch, nwg);
    }
  }
}

// Round 17
// 589.168 us; speedup vs baseline: 1.5052x; 1.0357x over previous
//
#include <hip/hip_runtime.h>

namespace {

constexpr int Bb = 8;
constexpr int Nn = 4097;
constexpr int Cc = 768;
constexpr int Hh = 12;
constexpr int HD = 64;
constexpr int Aa = 49;
constexpr int LDQ = 3 * Cc;        // 2304 (qkv row stride)
constexpr int NCH = 16;            // j-chunks for agent attention
constexpr int CHUNK = 256;         // 64-aligned; last chunk absorbs row 4096
constexpr float SCALE = 0.125f;    // hd^-0.5
constexpr int KP = 1536;           // WEIGHT packed row length (hi 768|lo 768)
constexpr int KA = 768;            // ACTIVATION packed row length (RNE bf16)

typedef short s16x8 __attribute__((ext_vector_type(8)));
typedef float f32x4 __attribute__((ext_vector_type(4)));

struct HL { short h, l; };

// Split fp32 into hi (truncated bf16, exact bits) + lo (RNE bf16 of residual).
__device__ inline HL splitbf(float v) {
  unsigned u = __float_as_uint(v);
  HL r;
  r.h = (short)(u >> 16);
  float hf = __uint_as_float(u & 0xffff0000u);
  float lf = v - hf;
  unsigned ul = __float_as_uint(lf);
  r.l = (short)((ul + 0x7fffu + ((ul >> 16) & 1u)) >> 16);
  return r;
}

__device__ inline short bf16rne(float v) {
  unsigned u = __float_as_uint(v);
  return (short)((u + 0x7fffu + ((u >> 16) & 1u)) >> 16);
}
__device__ inline float bf2f(unsigned short s) {
  return __uint_as_float((unsigned)s << 16);
}

// async global->LDS, 16B per lane (linear dest)
__device__ inline void gload16(const short* g, void* l) {
  __builtin_amdgcn_global_load_lds(
      (const __attribute__((address_space(1))) void*)g,
      (__attribute__((address_space(3))) void*)l, 16, 0, 0);
}

// Packed layout: per row, 12 windows of 64 elems (8 chunks of 8);
// physical chunk = logical chunk ^ (row&7).
// Weights: [N][1536] = [hi | lo] split (REQUIRED: RNE-only W gives ~3e-3
// max error through K=768 — fails). Activations: [M][768] single RNE.
// Attention operands (K,V,ah,av,P): single RNE — softmax averaging
// attenuates their error to ~1e-4 at the output.

// ---------------------------------------------------------------------------
// Pack activations: src[M][768] fp32 -> dst[M][768] RNE bf16.
// ---------------------------------------------------------------------------
__global__ __launch_bounds__(256) void pack_act(
    const float* __restrict__ src, short* __restrict__ dst, int M) {
  int idx = blockIdx.x * 256 + threadIdx.x;
  if (idx >= M * 96) return;
  int m = idx / 96, kc = idx - m * 96;
  const float* s = src + (size_t)m * 768 + kc * 8;
  float4 v0 = *(const float4*)s;
  float4 v1 = *(const float4*)(s + 4);
  s16x8 hv;
  hv[0] = bf16rne(v0.x); hv[1] = bf16rne(v0.y);
  hv[2] = bf16rne(v0.z); hv[3] = bf16rne(v0.w);
  hv[4] = bf16rne(v1.x); hv[5] = bf16rne(v1.y);
  hv[6] = bf16rne(v1.z); hv[7] = bf16rne(v1.w);
  int win = (kc >> 3) * 64;
  int jj = ((kc & 7) ^ (m & 7)) * 8;
  *(s16x8*)&dst[(size_t)m * KA + win + jj] = hv;
}

// ---------------------------------------------------------------------------
// Pack weights: W[768][N] fp32 -> Wpk[N][1536] bf16 split, key (n&7).
// ---------------------------------------------------------------------------
__global__ __launch_bounds__(256) void pack_w(
    const float* __restrict__ W, short* __restrict__ Wpk, int N) {
  int idx = blockIdx.x * 256 + threadIdx.x;
  if (idx >= 96 * N) return;
  int kc = idx / N, n = idx - kc * N;
  s16x8 hv, lv;
#pragma unroll
  for (int i = 0; i < 8; ++i) {
    HL r = splitbf(W[(size_t)(kc * 8 + i) * N + n]);
    hv[i] = r.h; lv[i] = r.l;
  }
  int win = (kc >> 3) * 64;
  int jj = ((kc & 7) ^ (n & 7)) * 8;
  short* d = Wpk + (size_t)n * KP;
  *(s16x8*)&d[win + jj] = hv;
  *(s16x8*)&d[768 + win + jj] = lv;
}

// ---------------------------------------------------------------------------
// C[M x N] = A @ B (+bias): A = RNE bf16 [M][768], B = split [N][1536].
// 2 products -> 64 MFMA per kt, 3 staged planes (48KB LDS). R12 barrier
// structure (frozen). 12 kt iterations. (unchanged from R16)
// ---------------------------------------------------------------------------
__global__ __launch_bounds__(256) void gemm_pk2(
    const short* __restrict__ Apk, const short* __restrict__ Bpk,
    float* __restrict__ Cm, const float* __restrict__ bias,
    int Mr, int ldc, int nch, int nwg) {
  __shared__ __align__(16) short AsH[128 * 64];
  __shared__ __align__(16) short BsH[128 * 64], BsL[128 * 64];
  const int t = threadIdx.x;
  const int lane = t & 63;
  const int w = t >> 6;
  const int wr = w >> 1, wc = w & 1;
  const int l15 = lane & 15, l4 = lane >> 4;

  const int j = blockIdx.x;
  const int q = nwg >> 3, r = nwg & 7;
  const int xcd = j & 7, pos = j >> 3;
  const int logical =
      (xcd < r ? xcd * (q + 1) : r * (q + 1) + (xcd - r) * q) + pos;
  const int mt = logical / nch, nc = logical - mt * nch;
  const int m0 = mt * 128, n0 = nc * 128;

  f32x4 acc[4][4];
#pragma unroll
  for (int mi = 0; mi < 4; ++mi)
#pragma unroll
    for (int ni = 0; ni < 4; ++ni) acc[mi][ni] = (f32x4){0.f, 0.f, 0.f, 0.f};

  for (int kt = 0; kt < 12; ++kt) {
    const short* Ab = Apk + (size_t)m0 * KA + kt * 64;
    const short* Bt = Bpk + (size_t)n0 * KP + kt * 64;
    __syncthreads();
#pragma unroll
    for (int i = 0; i < 4; ++i) {
      const int o = (i * 256 + t) * 16;   // byte offset in 16KB plane
      const int row = o >> 7;
      const int ce = (o & 127) >> 1;      // element col (physical)
      gload16(Ab + (size_t)row * KA + ce, (char*)AsH + o);
      gload16(Bt + (size_t)row * KP + ce, (char*)BsH + o);
      gload16(Bt + (size_t)row * KP + 768 + ce, (char*)BsL + o);
    }
    __syncthreads();
#pragma unroll
    for (int ks = 0; ks < 2; ++ks) {
      s16x8 ah[4], bh[4], bl[4];
#pragma unroll
      for (int mi = 0; mi < 4; ++mi) {
        int rr = wr * 64 + mi * 16 + l15;
        ah[mi] = *(const s16x8*)&AsH[rr * 64 + ((((ks << 2) + l4) ^ (l15 & 7)) << 3)];
      }
#pragma unroll
      for (int ni = 0; ni < 4; ++ni) {
        int rr = wc * 64 + ni * 16 + l15;
        int off = rr * 64 + ((((ks << 2) + l4) ^ (l15 & 7)) << 3);
        bh[ni] = *(const s16x8*)&BsH[off];
        bl[ni] = *(const s16x8*)&BsL[off];
      }
#pragma unroll
      for (int mi = 0; mi < 4; ++mi)
#pragma unroll
        for (int ni = 0; ni < 4; ++ni) {
          acc[mi][ni] = __builtin_amdgcn_mfma_f32_16x16x32_bf16(
              ah[mi], bh[ni], acc[mi][ni], 0, 0, 0);
          acc[mi][ni] = __builtin_amdgcn_mfma_f32_16x16x32_bf16(
              ah[mi], bl[ni], acc[mi][ni], 0, 0, 0);
        }
    }
  }

#pragma unroll
  for (int mi = 0; mi < 4; ++mi) {
#pragma unroll
    for (int jr = 0; jr < 4; ++jr) {
      int gr = m0 + wr * 64 + mi * 16 + l4 * 4 + jr;
      if (gr < Mr) {
#pragma unroll
        for (int ni = 0; ni < 4; ++ni) {
          int gc = n0 + wc * 64 + ni * 16 + l15;
          float v = acc[mi][ni][jr];
          if (bias) v += bias[gc];
          Cm[(size_t)gr * ldc + gc] = v;
        }
      }
    }
  }
}

// ---------------------------------------------------------------------------
// Adaptive-pool agents: at[bg,a,c] = mean over q rows [s,e) of q[bg,l,c].
// ---------------------------------------------------------------------------
__global__ __launch_bounds__(192) void pool_agents(
    const float* __restrict__ qkv, float* __restrict__ at) {
  const int ba = blockIdx.x;
  const int bg = ba / Aa, a = ba % Aa;
  const int s = (a * 4096) / 49;
  const int e = ((a + 1) * 4096 + 48) / 49;
  const float w = 1.0f / (float)(e - s);
  const int c4 = threadIdx.x * 4;
  f32x4 sum = (f32x4){0.f, 0.f, 0.f, 0.f};
#pragma unroll 4
  for (int l = s; l < e; ++l) {
    const float4 v = *(const float4*)&qkv[(size_t)(bg * Nn + l) * LDQ + c4];
    sum[0] += v.x; sum[1] += v.y; sum[2] += v.z; sum[3] += v.w;
  }
  float4 o;
  o.x = sum[0] * w; o.y = sum[1] * w; o.z = sum[2] * w; o.w = sum[3] * w;
  *(float4*)&at[(size_t)(bg * Aa + a) * Cc + c4] = o;
}

// ---------------------------------------------------------------------------
// Agent attention: ALL operands single RNE bf16 (softmax-attenuated error).
// S: 1 MFMA, PV: 1 MFMA per frag. 24KB LDS -> 6 blocks/CU. 3 barriers/tile.
// ---------------------------------------------------------------------------
__global__ __launch_bounds__(256) void agent_attn_mfma(
    const float* __restrict__ qkv, const float* __restrict__ at,
    float* __restrict__ paccv, float* __restrict__ paccs) {
  const int chunk = blockIdx.x, h = blockIdx.y, bg = blockIdx.z;
  __shared__ __align__(16) short AhH[4096];   // ah [a][d] RNE
  __shared__ __align__(16) short KH[4096];    // K [j][d] RNE; P aliases
  __shared__ __align__(16) short VtH[4096];   // V^T [c][j] RNE
  const int t = threadIdx.x;
  const int w = t >> 6, lane = t & 63, l15 = lane & 15, l4 = lane >> 4;

  for (int idx = t; idx < 512; idx += 256) {
    int a = idx >> 3, c8 = idx & 7;
    float vals[8];
    if (a < Aa) {
      const float* src = &at[(size_t)(bg * Aa + a) * Cc + h * HD + c8 * 8];
      *(float4*)&vals[0] = *(const float4*)src;
      *(float4*)&vals[4] = *(const float4*)(src + 4);
    } else {
#pragma unroll
      for (int i = 0; i < 8; ++i) vals[i] = 0.f;
    }
    s16x8 hv;
#pragma unroll
    for (int i = 0; i < 8; ++i) hv[i] = bf16rne(vals[i]);
    *(s16x8*)&AhH[a * 64 + ((c8 ^ (a & 7)) << 3)] = hv;
  }

  f32x4 acc[4];
#pragma unroll
  for (int ni = 0; ni < 4; ++ni) acc[ni] = (f32x4){0.f, 0.f, 0.f, 0.f};
  float rs[4] = {0.f, 0.f, 0.f, 0.f};

  const int jstart = chunk * CHUNK;
  const int jend = (chunk == NCH - 1) ? Nn : jstart + CHUNK;
  const int srow = t >> 2, sc0 = (t & 3) * 16;

  for (int j0 = jstart; j0 < jend; j0 += 64) {
    __syncthreads();   // prev tile's S/PV reads done
    {
      int jg = j0 + srow;
      float kv[16], vv[16];
      if (jg < jend) {
        const float* p = &qkv[(size_t)(bg * Nn + jg) * LDQ + Cc + h * HD + sc0];
#pragma unroll
        for (int r = 0; r < 4; ++r) {
          *(float4*)&kv[r * 4] = *(const float4*)(p + r * 4);
          *(float4*)&vv[r * 4] = *(const float4*)(p + Cc + r * 4);
        }
      } else {
#pragma unroll
        for (int i = 0; i < 16; ++i) { kv[i] = 0.f; vv[i] = 0.f; }
      }
#pragma unroll
      for (int r = 0; r < 2; ++r) {
        s16x8 hv;
#pragma unroll
        for (int i = 0; i < 8; ++i) hv[i] = bf16rne(kv[r * 8 + i]);
        int ch = (sc0 >> 3) + r;
        *(s16x8*)&KH[srow * 64 + ((ch ^ (srow & 7)) << 3)] = hv;
      }
#pragma unroll
      for (int i = 0; i < 16; ++i) {
        int c = sc0 + i;
        VtH[c * 64 + ((((srow >> 3) ^ (c & 7)) << 3)) + (srow & 7)] =
            bf16rne(vv[i]);
      }
    }
    __syncthreads();   // staged K/V visible

    f32x4 s[4];
#pragma unroll
    for (int ni = 0; ni < 4; ++ni) s[ni] = (f32x4){0.f, 0.f, 0.f, 0.f};
#pragma unroll
    for (int ks = 0; ks < 2; ++ks) {
      int sw = (((ks << 2) + l4) ^ (l15 & 7)) << 3;
      s16x8 ahh = *(const s16x8*)&AhH[(w * 16 + l15) * 64 + sw];
#pragma unroll
      for (int ni = 0; ni < 4; ++ni) {
        s16x8 kh = *(const s16x8*)&KH[(ni * 16 + l15) * 64 + sw];
        s[ni] = __builtin_amdgcn_mfma_f32_16x16x32_bf16(ahh, kh, s[ni], 0, 0, 0);
      }
    }
    __syncthreads();   // all waves done reading K -> P may overwrite KH

    // P = exp (masked), RNE; transpose-write into KH (wave-local rows).
#pragma unroll
    for (int ni = 0; ni < 4; ++ni) {
#pragma unroll
      for (int reg = 0; reg < 4; ++reg) {
        int jj = l15 + 16 * ni;
        float pv = (j0 + jj < jend) ? expf(s[ni][reg] * SCALE) : 0.f;
        rs[reg] += pv;
        int a = w * 16 + l4 * 4 + reg;
        KH[a * 64 + ((((jj >> 3) ^ (a & 7)) << 3)) + (jj & 7)] = bf16rne(pv);
      }
    }

    // O += P @ V (P reads wave-local)
#pragma unroll
    for (int ks = 0; ks < 2; ++ks) {
      int sw = (((ks << 2) + l4) ^ (l15 & 7)) << 3;
      s16x8 ph = *(const s16x8*)&KH[(w * 16 + l15) * 64 + sw];
#pragma unroll
      for (int ni = 0; ni < 4; ++ni) {
        s16x8 vh = *(const s16x8*)&VtH[(ni * 16 + l15) * 64 + sw];
        acc[ni] = __builtin_amdgcn_mfma_f32_16x16x32_bf16(ph, vh, acc[ni], 0, 0, 0);
      }
    }
  }

#pragma unroll
  for (int reg = 0; reg < 4; ++reg) {
    rs[reg] += __shfl_xor(rs[reg], 1);
    rs[reg] += __shfl_xor(rs[reg], 2);
    rs[reg] += __shfl_xor(rs[reg], 4);
    rs[reg] += __shfl_xor(rs[reg], 8);
  }
  const int basev = ((bg * Hh + h) * NCH + chunk) * (Aa * 64);
#pragma unroll
  for (int reg = 0; reg < 4; ++reg) {
    int a = w * 16 + l4 * 4 + reg;
    if (a < Aa) {
#pragma unroll
      for (int ni = 0; ni < 4; ++ni)
        paccv[basev + a * 64 + l15 + 16 * ni] = acc[ni][reg];
      if (l15 == 0)
        paccs[((bg * Hh + h) * NCH + chunk) * Aa + a] = rs[reg];
    }
  }
}

// ---------------------------------------------------------------------------
// Merge chunk partials -> agent_v[bgh,a,c]
// ---------------------------------------------------------------------------
__global__ __launch_bounds__(256) void merge_agent(
    const float* __restrict__ paccv, const float* __restrict__ paccs,
    float* __restrict__ av) {
  const int bh = blockIdx.x;
  const int t = threadIdx.x;
  for (int idx = t; idx < Aa * HD; idx += 256) {
    int a = idx >> 6;
    float vs = 0.f, ss = 0.f;
#pragma unroll
    for (int ch = 0; ch < NCH; ++ch) {
      vs += paccv[(size_t)((bh * NCH + ch)) * (Aa * 64) + idx];
      ss += paccs[(bh * NCH + ch) * Aa + a];
    }
    av[(size_t)bh * (Aa * HD) + idx] = vs / ss;
  }
}

// ---------------------------------------------------------------------------
// FUSED q attention + dwc + pack. ALL operands single RNE bf16.
// S: 1 MFMA, PV: 1 MFMA. ~27KB LDS. Epilogue: O->LDS, re-gather, 16B stores.
// ---------------------------------------------------------------------------
__global__ __launch_bounds__(256) void q_attn_dwc(
    const float* __restrict__ qkv, const float* __restrict__ at,
    const float* __restrict__ av, const float* __restrict__ dwcw,
    const float* __restrict__ dwcb, short* __restrict__ Opk) {
  const int i0 = blockIdx.x * 64, h = blockIdx.y, bg = blockIdx.z;
  __shared__ __align__(16) short SMEM[13568];   // 27136B
  short* AhH = SMEM;             // ah [a][d] RNE   (8KB)
  short* AvH = SMEM + 4096;      // av^T [c][a] RNE (8KB)
  short* QH  = SMEM + 8192;      // q [row][d] RNE; P alias (8KB)
  const int t = threadIdx.x;
  const int w = t >> 6, lane = t & 63, l15 = lane & 15, l4 = lane >> 4;

  for (int idx = t; idx < 512; idx += 256) {
    int a = idx >> 3, c8 = idx & 7;
    float vah[8], vav[8];
    if (a < Aa) {
      const float* s1 = &at[(size_t)(bg * Aa + a) * Cc + h * HD + c8 * 8];
      const float* s2 = &av[(size_t)(bg * Hh + h) * (Aa * HD) + a * HD + c8 * 8];
      *(float4*)&vah[0] = *(const float4*)s1;
      *(float4*)&vah[4] = *(const float4*)(s1 + 4);
      *(float4*)&vav[0] = *(const float4*)s2;
      *(float4*)&vav[4] = *(const float4*)(s2 + 4);
    } else {
#pragma unroll
      for (int i = 0; i < 8; ++i) { vah[i] = 0.f; vav[i] = 0.f; }
    }
    s16x8 hv;
#pragma unroll
    for (int i = 0; i < 8; ++i) hv[i] = bf16rne(vah[i]);
    *(s16x8*)&AhH[a * 64 + ((c8 ^ (a & 7)) << 3)] = hv;
#pragma unroll
    for (int i = 0; i < 8; ++i) {
      int c = c8 * 8 + i;
      AvH[c * 64 + ((((a >> 3) ^ (c & 7)) << 3)) + (a & 7)] = bf16rne(vav[i]);
    }
  }
  {
    int row = t >> 2, c0 = (t & 3) * 16;
    int ig = i0 + row;
    float qv[16];
    if (ig < Nn) {
      const float* p = &qkv[(size_t)(bg * Nn + ig) * LDQ + h * HD + c0];
#pragma unroll
      for (int r = 0; r < 4; ++r) *(float4*)&qv[r * 4] = *(const float4*)(p + r * 4);
    } else {
#pragma unroll
      for (int i = 0; i < 16; ++i) qv[i] = 0.f;
    }
#pragma unroll
    for (int r = 0; r < 2; ++r) {
      s16x8 hv;
#pragma unroll
      for (int i = 0; i < 8; ++i) hv[i] = bf16rne(qv[r * 8 + i]);
      int ch = (c0 >> 3) + r;
      *(s16x8*)&QH[row * 64 + ((ch ^ (row & 7)) << 3)] = hv;
    }
  }
  __syncthreads();

  // ---- S = q @ ah^T (1 product) ----
  f32x4 s[4];
#pragma unroll
  for (int ni = 0; ni < 4; ++ni) s[ni] = (f32x4){0.f, 0.f, 0.f, 0.f};
#pragma unroll
  for (int ks = 0; ks < 2; ++ks) {
    int sw = (((ks << 2) + l4) ^ (l15 & 7)) << 3;
    s16x8 qh = *(const s16x8*)&QH[(w * 16 + l15) * 64 + sw];
#pragma unroll
    for (int ni = 0; ni < 4; ++ni) {
      s16x8 bh = *(const s16x8*)&AhH[(ni * 16 + l15) * 64 + sw];
      s[ni] = __builtin_amdgcn_mfma_f32_16x16x32_bf16(qh, bh, s[ni], 0, 0, 0);
    }
  }
  __syncthreads();  // all waves done reading Q -> P may overwrite

  // ---- softmax over agents + transpose-write P (RNE) into QH ----
  float rsum[4] = {0.f, 0.f, 0.f, 0.f};
#pragma unroll
  for (int ni = 0; ni < 4; ++ni) {
#pragma unroll
    for (int reg = 0; reg < 4; ++reg) {
      int a = l15 + 16 * ni;
      float pv = (a < Aa) ? expf(s[ni][reg] * SCALE) : 0.f;
      s[ni][reg] = pv;
      rsum[reg] += pv;
    }
  }
#pragma unroll
  for (int reg = 0; reg < 4; ++reg) {
    rsum[reg] += __shfl_xor(rsum[reg], 1);
    rsum[reg] += __shfl_xor(rsum[reg], 2);
    rsum[reg] += __shfl_xor(rsum[reg], 4);
    rsum[reg] += __shfl_xor(rsum[reg], 8);
    rsum[reg] = 1.0f / rsum[reg];
  }
#pragma unroll
  for (int ni = 0; ni < 4; ++ni) {
#pragma unroll
    for (int reg = 0; reg < 4; ++reg) {
      int row = w * 16 + l4 * 4 + reg;
      int a = l15 + 16 * ni;
      QH[row * 64 + ((((a >> 3) ^ (row & 7)) << 3)) + (a & 7)] =
          bf16rne(s[ni][reg] * rsum[reg]);
    }
  }
  __syncthreads();

  // ---- O = P @ agent_v (1 product) ----
  f32x4 o[4];
#pragma unroll
  for (int ni = 0; ni < 4; ++ni) o[ni] = (f32x4){0.f, 0.f, 0.f, 0.f};
#pragma unroll
  for (int ks = 0; ks < 2; ++ks) {
    int sw = (((ks << 2) + l4) ^ (l15 & 7)) << 3;
    s16x8 ph = *(const s16x8*)&QH[(w * 16 + l15) * 64 + sw];
#pragma unroll
    for (int ni = 0; ni < 4; ++ni) {
      s16x8 vh = *(const s16x8*)&AvH[(ni * 16 + l15) * 64 + sw];
      o[ni] = __builtin_amdgcn_mfma_f32_16x16x32_bf16(ph, vh, o[ni], 0, 0, 0);
    }
  }
  __syncthreads();  // all LDS dead -> olds / vlds may overwrite

  // ---- write O to LDS (stride 68) + stage v tile (bf16) ----
  float* olds = (float*)SMEM;                              // 17408B
  unsigned short* vlds = (unsigned short*)(SMEM + 8704);   // 9504B, disjoint
#pragma unroll
  for (int reg = 0; reg < 4; ++reg) {
    int row = w * 16 + l4 * 4 + reg;
#pragma unroll
    for (int ni = 0; ni < 4; ++ni)
      olds[row * 68 + l15 + 16 * ni] = o[ni][reg];
  }
  constexpr int VLD = 72;
  for (int idx = t; idx < 66 * 16; idx += 256) {
    int row = idx >> 4, cs = (idx & 15) << 2;
    int gr = i0 - 1 + row;
    float4 v = make_float4(0.f, 0.f, 0.f, 0.f);
    if (gr >= 0 && gr < 4096)
      v = *(const float4*)&qkv[((size_t)bg * Nn + gr) * LDQ + 2 * Cc + h * HD + cs];
    unsigned short* d = &vlds[row * VLD + cs];
    d[0] = (unsigned short)bf16rne(v.x); d[1] = (unsigned short)bf16rne(v.y);
    d[2] = (unsigned short)bf16rne(v.z); d[3] = (unsigned short)bf16rne(v.w);
  }
  __syncthreads();

  // ---- re-gather: (local row, 8-ch chunk) -> one 16B store ----
#pragma unroll
  for (int it = 0; it < 2; ++it) {
    int widx = t + it * 256;            // 0..511
    int ml = widx >> 3, kc = widx & 7;
    int ig = i0 + ml;
    if (ig >= Nn) continue;
    float vals[8];
    *(float4*)&vals[0] = *(const float4*)&olds[ml * 68 + kc * 8];
    *(float4*)&vals[4] = *(const float4*)&olds[ml * 68 + kc * 8 + 4];
    if (ig < Nn - 1) {
      const int rl = ml + 1;
      const unsigned short* vr = &vlds[rl * VLD + kc * 8];
#pragma unroll
      for (int cI = 0; cI < 8; ++cI) {
        int cg = h * HD + kc * 8 + cI;
        float vm = bf2f(vr[cI - VLD]);
        float v0 = bf2f(vr[cI]);
        float vp = bf2f(vr[cI + VLD]);
        vals[cI] += dwcw[cg * 3] * vm + dwcw[cg * 3 + 1] * v0 +
                    dwcw[cg * 3 + 2] * vp + dwcb[cg];
      }
    }
    s16x8 hv;
#pragma unroll
    for (int cI = 0; cI < 8; ++cI) hv[cI] = bf16rne(vals[cI]);
    const int mrow = bg * Nn + ig;
    const int win = h * 64;
    const int jj = (kc ^ (mrow & 7)) * 8;
    *(s16x8*)&Opk[(size_t)mrow * KA + win + jj] = hv;
  }
}

}  // namespace

extern "C" void kernel_launch(void* const* d_in, const int* in_sizes, int n_in,
                              void* d_out, int out_size, void* d_ws,
                              size_t ws_size, hipStream_t stream) {
  const float* x = (const float*)d_in[0];
  const float* Wqkv = (const float*)d_in[1];
  const float* Wproj = (const float*)d_in[2];
  const float* bproj = (const float*)d_in[3];
  const float* dwcw = (const float*)d_in[4];
  const float* dwcb = (const float*)d_in[5];
  float* out = (float*)d_out;

  // --- fixed workspace: packed weight planes ---
  char* p = (char*)d_ws;
  short* WQpk = (short*)p; p += (size_t)LDQ * KP * 2;   // 7,077,888 B
  short* WPpk = (short*)p; p += (size_t)Cc * KP * 2;    // 2,359,296 B
  const size_t fixedBytes = (size_t)p - (size_t)d_ws;

  auto bytesFor = [&](int G) -> size_t {
    size_t Mg = (size_t)G * Nn;
    size_t Mpad = ((Mg + 127) / 128) * 128;
    size_t fl = Mg * LDQ +
                (size_t)G * (Aa * Cc + Hh * NCH * Aa * 64 + Hh * NCH * Aa +
                             Hh * Aa * HD);
    return fixedBytes + fl * 4 + Mpad * KA * 2;            // + Apk/Opk (RNE)
  };
  int G = 1;
  for (int g = Bb; g >= 1; --g) {
    if (bytesFor(g) <= ws_size) { G = g; break; }
  }

  const size_t MgMax = (size_t)G * Nn;
  float* qkv = (float*)p;
  float* at = qkv + MgMax * LDQ;
  float* paccv = at + (size_t)G * Aa * Cc;
  float* paccs = paccv + (size_t)G * Hh * NCH * Aa * 64;
  float* av = paccs + (size_t)G * Hh * NCH * Aa;
  short* Apk = (short*)(av + (size_t)G * Hh * Aa * HD);   // aliased as Opk

  dim3 blk(256);
  // 0) pack weights (once per launch; deterministic)
  pack_w<<<dim3((96 * LDQ + 255) / 256), blk, 0, stream>>>(Wqkv, WQpk, LDQ);
  pack_w<<<dim3((96 * Cc + 255) / 256), blk, 0, stream>>>(Wproj, WPpk, Cc);

  for (int b0 = 0; b0 < Bb; b0 += G) {
    const int Gi = (b0 + G <= Bb) ? G : (Bb - b0);
    const int Mg = Gi * Nn;
    const int Mtiles = (Mg + 127) / 128;
    const float* xg = x + (size_t)b0 * Nn * Cc;
    float* outg = out + (size_t)b0 * Nn * Cc;

    // 1) pack x (RNE) -> Apk, then qkv = x @ Wqkv
    pack_act<<<dim3((Mg * 96 + 255) / 256), blk, 0, stream>>>(xg, Apk, Mg);
    {
      const int nch = LDQ / 128;            // 18
      const int nwg = Mtiles * nch;
      gemm_pk2<<<dim3(nwg), blk, 0, stream>>>(Apk, WQpk, qkv, nullptr, Mg,
                                              LDQ, nch, nwg);
    }
    // 2) agent tokens (adaptive pool of q)
    pool_agents<<<dim3(Gi * Aa), dim3(192), 0, stream>>>(qkv, at);
    // 3) agent attention partials (MFMA) + merge -> agent_v
    agent_attn_mfma<<<dim3(NCH, Hh, Gi), blk, 0, stream>>>(qkv, at, paccv,
                                                           paccs);
    merge_agent<<<dim3(Gi * Hh), blk, 0, stream>>>(paccv, paccs, av);
    // 4) fused q attention + dwc + pack (RNE) -> Opk(=Apk)
    q_attn_dwc<<<dim3((Nn + 63) / 64, Hh, Gi), blk, 0, stream>>>(
        qkv, at, av, dwcw, dwcb, Apk);
    // 5) final projection -> out_g (+bias)
    {
      const int nch = Cc / 128;             // 6
      const int nwg = Mtiles * nch;
      gemm_pk2<<<dim3(nwg), blk, 0, stream>>>(Apk, WPpk, outg, bproj, Mg,
                                              Cc, nch, nwg);
    }
  }
}

// Round 18
// 523.680 us; speedup vs baseline: 1.6934x; 1.1251x over previous
//
#include <hip/hip_runtime.h>

namespace {

constexpr int Bb = 8;
constexpr int Nn = 4097;
constexpr int Cc = 768;
constexpr int Hh = 12;
constexpr int HD = 64;
constexpr int Aa = 49;
constexpr int LDQ = 3 * Cc;        // 2304 (qkv row stride, now in shorts)
constexpr int NCH = 16;            // j-chunks for agent attention
constexpr int CHUNK = 256;         // 64-aligned; last chunk absorbs row 4096
constexpr float SCALE = 0.125f;    // hd^-0.5
constexpr int KP = 1536;           // WEIGHT packed row length (hi 768|lo 768)
constexpr int KA = 768;            // ACTIVATION packed row length (RNE bf16)

typedef short s16x8 __attribute__((ext_vector_type(8)));
typedef short s16x4 __attribute__((ext_vector_type(4)));
typedef float f32x4 __attribute__((ext_vector_type(4)));

struct HL { short h, l; };

// Split fp32 into hi (truncated bf16, exact bits) + lo (RNE bf16 of residual).
__device__ inline HL splitbf(float v) {
  unsigned u = __float_as_uint(v);
  HL r;
  r.h = (short)(u >> 16);
  float hf = __uint_as_float(u & 0xffff0000u);
  float lf = v - hf;
  unsigned ul = __float_as_uint(lf);
  r.l = (short)((ul + 0x7fffu + ((ul >> 16) & 1u)) >> 16);
  return r;
}

__device__ inline short bf16rne(float v) {
  unsigned u = __float_as_uint(v);
  return (short)((u + 0x7fffu + ((u >> 16) & 1u)) >> 16);
}
__device__ inline float bf2f(short s) {
  return __uint_as_float((unsigned)(unsigned short)s << 16);
}

// async global->LDS, 16B per lane (linear dest)
__device__ inline void gload16(const short* g, void* l) {
  __builtin_amdgcn_global_load_lds(
      (const __attribute__((address_space(1))) void*)g,
      (__attribute__((address_space(3))) void*)l, 16, 0, 0);
}

// Packed layout: per row, 12 windows of 64 elems (8 chunks of 8);
// physical chunk = logical chunk ^ (row&7).
// Weights: split hi/lo (REQUIRED — RNE-only W fails threshold through K=768).
// Activations/attention operands: single RNE bf16 (softmax-attenuated error).
// qkv / at / av are STORED as RNE bf16: every consumer RNE'd them anyway, so
// this is bit-identical except pool_agents (averages rounded q; negligible).

// ---------------------------------------------------------------------------
// Pack activations: src[M][768] fp32 -> dst[M][768] RNE bf16 (swizzled).
// ---------------------------------------------------------------------------
__global__ __launch_bounds__(256) void pack_act(
    const float* __restrict__ src, short* __restrict__ dst, int M) {
  int idx = blockIdx.x * 256 + threadIdx.x;
  if (idx >= M * 96) return;
  int m = idx / 96, kc = idx - m * 96;
  const float* s = src + (size_t)m * 768 + kc * 8;
  float4 v0 = *(const float4*)s;
  float4 v1 = *(const float4*)(s + 4);
  s16x8 hv;
  hv[0] = bf16rne(v0.x); hv[1] = bf16rne(v0.y);
  hv[2] = bf16rne(v0.z); hv[3] = bf16rne(v0.w);
  hv[4] = bf16rne(v1.x); hv[5] = bf16rne(v1.y);
  hv[6] = bf16rne(v1.z); hv[7] = bf16rne(v1.w);
  int win = (kc >> 3) * 64;
  int jj = ((kc & 7) ^ (m & 7)) * 8;
  *(s16x8*)&dst[(size_t)m * KA + win + jj] = hv;
}

// ---------------------------------------------------------------------------
// Pack weights: W[768][N] fp32 -> Wpk[N][1536] bf16 split, key (n&7).
// ---------------------------------------------------------------------------
__global__ __launch_bounds__(256) void pack_w(
    const float* __restrict__ W, short* __restrict__ Wpk, int N) {
  int idx = blockIdx.x * 256 + threadIdx.x;
  if (idx >= 96 * N) return;
  int kc = idx / N, n = idx - kc * N;
  s16x8 hv, lv;
#pragma unroll
  for (int i = 0; i < 8; ++i) {
    HL r = splitbf(W[(size_t)(kc * 8 + i) * N + n]);
    hv[i] = r.h; lv[i] = r.l;
  }
  int win = (kc >> 3) * 64;
  int jj = ((kc & 7) ^ (n & 7)) * 8;
  short* d = Wpk + (size_t)n * KP;
  *(s16x8*)&d[win + jj] = hv;
  *(s16x8*)&d[768 + win + jj] = lv;
}

// ---------------------------------------------------------------------------
// C[M x N] = A @ B (+bias): A = RNE bf16 [M][768], B = split [N][1536].
// 2 products -> 64 MFMA per kt, 3 staged planes (48KB LDS). R12 barrier
// structure (frozen). BF16OUT: store RNE bf16 (qkv); else fp32 (final out).
// ---------------------------------------------------------------------------
template <bool BF16OUT>
__global__ __launch_bounds__(256) void gemm_pk2(
    const short* __restrict__ Apk, const short* __restrict__ Bpk,
    void* __restrict__ Cm, const float* __restrict__ bias,
    int Mr, int ldc, int nch, int nwg) {
  __shared__ __align__(16) short AsH[128 * 64];
  __shared__ __align__(16) short BsH[128 * 64], BsL[128 * 64];
  const int t = threadIdx.x;
  const int lane = t & 63;
  const int w = t >> 6;
  const int wr = w >> 1, wc = w & 1;
  const int l15 = lane & 15, l4 = lane >> 4;

  const int j = blockIdx.x;
  const int q = nwg >> 3, r = nwg & 7;
  const int xcd = j & 7, pos = j >> 3;
  const int logical =
      (xcd < r ? xcd * (q + 1) : r * (q + 1) + (xcd - r) * q) + pos;
  const int mt = logical / nch, nc = logical - mt * nch;
  const int m0 = mt * 128, n0 = nc * 128;

  f32x4 acc[4][4];
#pragma unroll
  for (int mi = 0; mi < 4; ++mi)
#pragma unroll
    for (int ni = 0; ni < 4; ++ni) acc[mi][ni] = (f32x4){0.f, 0.f, 0.f, 0.f};

  for (int kt = 0; kt < 12; ++kt) {
    const short* Ab = Apk + (size_t)m0 * KA + kt * 64;
    const short* Bt = Bpk + (size_t)n0 * KP + kt * 64;
    __syncthreads();
#pragma unroll
    for (int i = 0; i < 4; ++i) {
      const int o = (i * 256 + t) * 16;   // byte offset in 16KB plane
      const int row = o >> 7;
      const int ce = (o & 127) >> 1;      // element col (physical)
      gload16(Ab + (size_t)row * KA + ce, (char*)AsH + o);
      gload16(Bt + (size_t)row * KP + ce, (char*)BsH + o);
      gload16(Bt + (size_t)row * KP + 768 + ce, (char*)BsL + o);
    }
    __syncthreads();
#pragma unroll
    for (int ks = 0; ks < 2; ++ks) {
      s16x8 ah[4], bh[4], bl[4];
#pragma unroll
      for (int mi = 0; mi < 4; ++mi) {
        int rr = wr * 64 + mi * 16 + l15;
        ah[mi] = *(const s16x8*)&AsH[rr * 64 + ((((ks << 2) + l4) ^ (l15 & 7)) << 3)];
      }
#pragma unroll
      for (int ni = 0; ni < 4; ++ni) {
        int rr = wc * 64 + ni * 16 + l15;
        int off = rr * 64 + ((((ks << 2) + l4) ^ (l15 & 7)) << 3);
        bh[ni] = *(const s16x8*)&BsH[off];
        bl[ni] = *(const s16x8*)&BsL[off];
      }
#pragma unroll
      for (int mi = 0; mi < 4; ++mi)
#pragma unroll
        for (int ni = 0; ni < 4; ++ni) {
          acc[mi][ni] = __builtin_amdgcn_mfma_f32_16x16x32_bf16(
              ah[mi], bh[ni], acc[mi][ni], 0, 0, 0);
          acc[mi][ni] = __builtin_amdgcn_mfma_f32_16x16x32_bf16(
              ah[mi], bl[ni], acc[mi][ni], 0, 0, 0);
        }
    }
  }

#pragma unroll
  for (int mi = 0; mi < 4; ++mi) {
#pragma unroll
    for (int jr = 0; jr < 4; ++jr) {
      int gr = m0 + wr * 64 + mi * 16 + l4 * 4 + jr;
      if (gr < Mr) {
#pragma unroll
        for (int ni = 0; ni < 4; ++ni) {
          int gc = n0 + wc * 64 + ni * 16 + l15;
          float v = acc[mi][ni][jr];
          if (bias) v += bias[gc];
          if constexpr (BF16OUT) {
            ((short*)Cm)[(size_t)gr * ldc + gc] = bf16rne(v);
          } else {
            ((float*)Cm)[(size_t)gr * ldc + gc] = v;
          }
        }
      }
    }
  }
}

// ---------------------------------------------------------------------------
// Adaptive-pool agents: atb[bg,a,c] = RNE(mean over q rows of bf16 q).
// ---------------------------------------------------------------------------
__global__ __launch_bounds__(192) void pool_agents(
    const short* __restrict__ qkvb, short* __restrict__ atb) {
  const int ba = blockIdx.x;
  const int bg = ba / Aa, a = ba % Aa;
  const int s = (a * 4096) / 49;
  const int e = ((a + 1) * 4096 + 48) / 49;
  const float w = 1.0f / (float)(e - s);
  const int c4 = threadIdx.x * 4;
  f32x4 sum = (f32x4){0.f, 0.f, 0.f, 0.f};
  for (int l = s; l < e; ++l) {
    const s16x4 v = *(const s16x4*)&qkvb[(size_t)(bg * Nn + l) * LDQ + c4];
    sum[0] += bf2f(v[0]); sum[1] += bf2f(v[1]);
    sum[2] += bf2f(v[2]); sum[3] += bf2f(v[3]);
  }
  s16x4 o;
  o[0] = bf16rne(sum[0] * w); o[1] = bf16rne(sum[1] * w);
  o[2] = bf16rne(sum[2] * w); o[3] = bf16rne(sum[3] * w);
  *(s16x4*)&atb[(size_t)(bg * Aa + a) * Cc + c4] = o;
}

// ---------------------------------------------------------------------------
// Agent attention: all operands RNE bf16, staging = direct bit-copy (no
// converts). 24KB LDS -> 6 blocks/CU. 3 barriers/tile.
// ---------------------------------------------------------------------------
__global__ __launch_bounds__(256) void agent_attn_mfma(
    const short* __restrict__ qkvb, const short* __restrict__ atb,
    float* __restrict__ paccv, float* __restrict__ paccs) {
  const int chunk = blockIdx.x, h = blockIdx.y, bg = blockIdx.z;
  __shared__ __align__(16) short AhH[4096];   // ah [a][d]
  __shared__ __align__(16) short KH[4096];    // K [j][d]; P aliases
  __shared__ __align__(16) short VtH[4096];   // V^T [c][j]
  const int t = threadIdx.x;
  const int w = t >> 6, lane = t & 63, l15 = lane & 15, l4 = lane >> 4;

  for (int idx = t; idx < 512; idx += 256) {
    int a = idx >> 3, c8 = idx & 7;
    s16x8 hv = (s16x8)(short)0;
    if (a < Aa)
      hv = *(const s16x8*)&atb[(size_t)(bg * Aa + a) * Cc + h * HD + c8 * 8];
    *(s16x8*)&AhH[a * 64 + ((c8 ^ (a & 7)) << 3)] = hv;
  }

  f32x4 acc[4];
#pragma unroll
  for (int ni = 0; ni < 4; ++ni) acc[ni] = (f32x4){0.f, 0.f, 0.f, 0.f};
  float rs[4] = {0.f, 0.f, 0.f, 0.f};

  const int jstart = chunk * CHUNK;
  const int jend = (chunk == NCH - 1) ? Nn : jstart + CHUNK;
  const int srow = t >> 2, sc0 = (t & 3) * 16;

  for (int j0 = jstart; j0 < jend; j0 += 64) {
    __syncthreads();   // prev tile's S/PV reads done
    {
      int jg = j0 + srow;
      s16x8 k0 = (s16x8)(short)0, k1 = k0, v0 = k0, v1 = k0;
      if (jg < jend) {
        const short* p = &qkvb[(size_t)(bg * Nn + jg) * LDQ + Cc + h * HD + sc0];
        k0 = *(const s16x8*)p;
        k1 = *(const s16x8*)(p + 8);
        v0 = *(const s16x8*)(p + Cc);
        v1 = *(const s16x8*)(p + Cc + 8);
      }
      int ch = sc0 >> 3;
      *(s16x8*)&KH[srow * 64 + (((ch + 0) ^ (srow & 7)) << 3)] = k0;
      *(s16x8*)&KH[srow * 64 + (((ch + 1) ^ (srow & 7)) << 3)] = k1;
#pragma unroll
      for (int i = 0; i < 8; ++i) {
        int c = sc0 + i;
        VtH[c * 64 + ((((srow >> 3) ^ (c & 7)) << 3)) + (srow & 7)] = v0[i];
      }
#pragma unroll
      for (int i = 0; i < 8; ++i) {
        int c = sc0 + 8 + i;
        VtH[c * 64 + ((((srow >> 3) ^ (c & 7)) << 3)) + (srow & 7)] = v1[i];
      }
    }
    __syncthreads();   // staged K/V visible

    f32x4 s[4];
#pragma unroll
    for (int ni = 0; ni < 4; ++ni) s[ni] = (f32x4){0.f, 0.f, 0.f, 0.f};
#pragma unroll
    for (int ks = 0; ks < 2; ++ks) {
      int sw = (((ks << 2) + l4) ^ (l15 & 7)) << 3;
      s16x8 ahh = *(const s16x8*)&AhH[(w * 16 + l15) * 64 + sw];
#pragma unroll
      for (int ni = 0; ni < 4; ++ni) {
        s16x8 kh = *(const s16x8*)&KH[(ni * 16 + l15) * 64 + sw];
        s[ni] = __builtin_amdgcn_mfma_f32_16x16x32_bf16(ahh, kh, s[ni], 0, 0, 0);
      }
    }
    __syncthreads();   // all waves done reading K -> P may overwrite KH

    // P = exp (masked), RNE; transpose-write into KH (wave-local rows).
#pragma unroll
    for (int ni = 0; ni < 4; ++ni) {
#pragma unroll
      for (int reg = 0; reg < 4; ++reg) {
        int jj = l15 + 16 * ni;
        float pv = (j0 + jj < jend) ? expf(s[ni][reg] * SCALE) : 0.f;
        rs[reg] += pv;
        int a = w * 16 + l4 * 4 + reg;
        KH[a * 64 + ((((jj >> 3) ^ (a & 7)) << 3)) + (jj & 7)] = bf16rne(pv);
      }
    }

    // O += P @ V (P reads wave-local)
#pragma unroll
    for (int ks = 0; ks < 2; ++ks) {
      int sw = (((ks << 2) + l4) ^ (l15 & 7)) << 3;
      s16x8 ph = *(const s16x8*)&KH[(w * 16 + l15) * 64 + sw];
#pragma unroll
      for (int ni = 0; ni < 4; ++ni) {
        s16x8 vh = *(const s16x8*)&VtH[(ni * 16 + l15) * 64 + sw];
        acc[ni] = __builtin_amdgcn_mfma_f32_16x16x32_bf16(ph, vh, acc[ni], 0, 0, 0);
      }
    }
  }

#pragma unroll
  for (int reg = 0; reg < 4; ++reg) {
    rs[reg] += __shfl_xor(rs[reg], 1);
    rs[reg] += __shfl_xor(rs[reg], 2);
    rs[reg] += __shfl_xor(rs[reg], 4);
    rs[reg] += __shfl_xor(rs[reg], 8);
  }
  const int basev = ((bg * Hh + h) * NCH + chunk) * (Aa * 64);
#pragma unroll
  for (int reg = 0; reg < 4; ++reg) {
    int a = w * 16 + l4 * 4 + reg;
    if (a < Aa) {
#pragma unroll
      for (int ni = 0; ni < 4; ++ni)
        paccv[basev + a * 64 + l15 + 16 * ni] = acc[ni][reg];
      if (l15 == 0)
        paccs[((bg * Hh + h) * NCH + chunk) * Aa + a] = rs[reg];
    }
  }
}

// ---------------------------------------------------------------------------
// Merge chunk partials -> avb[bgh,a,c] (RNE bf16)
// ---------------------------------------------------------------------------
__global__ __launch_bounds__(256) void merge_agent(
    const float* __restrict__ paccv, const float* __restrict__ paccs,
    short* __restrict__ avb) {
  const int bh = blockIdx.x;
  const int t = threadIdx.x;
  for (int idx = t; idx < Aa * HD; idx += 256) {
    int a = idx >> 6;
    float vs = 0.f, ss = 0.f;
#pragma unroll
    for (int ch = 0; ch < NCH; ++ch) {
      vs += paccv[(size_t)((bh * NCH + ch)) * (Aa * 64) + idx];
      ss += paccs[(bh * NCH + ch) * Aa + a];
    }
    avb[(size_t)bh * (Aa * HD) + idx] = bf16rne(vs / ss);
  }
}

// ---------------------------------------------------------------------------
// FUSED q attention + dwc + pack. All operands RNE bf16; staging = copies.
// ~27KB LDS. Epilogue: O->LDS, re-gather, 16B stores to Opk.
// ---------------------------------------------------------------------------
__global__ __launch_bounds__(256) void q_attn_dwc(
    const short* __restrict__ qkvb, const short* __restrict__ atb,
    const short* __restrict__ avb, const float* __restrict__ dwcw,
    const float* __restrict__ dwcb, short* __restrict__ Opk) {
  const int i0 = blockIdx.x * 64, h = blockIdx.y, bg = blockIdx.z;
  __shared__ __align__(16) short SMEM[13568];   // 27136B
  short* AhH = SMEM;             // ah [a][d]   (8KB)
  short* AvH = SMEM + 4096;      // av^T [c][a] (8KB)
  short* QH  = SMEM + 8192;      // q [row][d]; P alias (8KB)
  const int t = threadIdx.x;
  const int w = t >> 6, lane = t & 63, l15 = lane & 15, l4 = lane >> 4;

  for (int idx = t; idx < 512; idx += 256) {
    int a = idx >> 3, c8 = idx & 7;
    s16x8 hv = (s16x8)(short)0, av8 = hv;
    if (a < Aa) {
      hv = *(const s16x8*)&atb[(size_t)(bg * Aa + a) * Cc + h * HD + c8 * 8];
      av8 = *(const s16x8*)&avb[(size_t)(bg * Hh + h) * (Aa * HD) + a * HD + c8 * 8];
    }
    *(s16x8*)&AhH[a * 64 + ((c8 ^ (a & 7)) << 3)] = hv;
#pragma unroll
    for (int i = 0; i < 8; ++i) {
      int c = c8 * 8 + i;
      AvH[c * 64 + ((((a >> 3) ^ (c & 7)) << 3)) + (a & 7)] = av8[i];
    }
  }
  {
    int row = t >> 2, c0 = (t & 3) * 16;
    int ig = i0 + row;
    s16x8 q0 = (s16x8)(short)0, q1 = q0;
    if (ig < Nn) {
      const short* p = &qkvb[(size_t)(bg * Nn + ig) * LDQ + h * HD + c0];
      q0 = *(const s16x8*)p;
      q1 = *(const s16x8*)(p + 8);
    }
    int ch = c0 >> 3;
    *(s16x8*)&QH[row * 64 + (((ch + 0) ^ (row & 7)) << 3)] = q0;
    *(s16x8*)&QH[row * 64 + (((ch + 1) ^ (row & 7)) << 3)] = q1;
  }
  __syncthreads();

  // ---- S = q @ ah^T (1 product) ----
  f32x4 s[4];
#pragma unroll
  for (int ni = 0; ni < 4; ++ni) s[ni] = (f32x4){0.f, 0.f, 0.f, 0.f};
#pragma unroll
  for (int ks = 0; ks < 2; ++ks) {
    int sw = (((ks << 2) + l4) ^ (l15 & 7)) << 3;
    s16x8 qh = *(const s16x8*)&QH[(w * 16 + l15) * 64 + sw];
#pragma unroll
    for (int ni = 0; ni < 4; ++ni) {
      s16x8 bh = *(const s16x8*)&AhH[(ni * 16 + l15) * 64 + sw];
      s[ni] = __builtin_amdgcn_mfma_f32_16x16x32_bf16(qh, bh, s[ni], 0, 0, 0);
    }
  }
  __syncthreads();  // all waves done reading Q -> P may overwrite

  // ---- softmax over agents + transpose-write P (RNE) into QH ----
  float rsum[4] = {0.f, 0.f, 0.f, 0.f};
#pragma unroll
  for (int ni = 0; ni < 4; ++ni) {
#pragma unroll
    for (int reg = 0; reg < 4; ++reg) {
      int a = l15 + 16 * ni;
      float pv = (a < Aa) ? expf(s[ni][reg] * SCALE) : 0.f;
      s[ni][reg] = pv;
      rsum[reg] += pv;
    }
  }
#pragma unroll
  for (int reg = 0; reg < 4; ++reg) {
    rsum[reg] += __shfl_xor(rsum[reg], 1);
    rsum[reg] += __shfl_xor(rsum[reg], 2);
    rsum[reg] += __shfl_xor(rsum[reg], 4);
    rsum[reg] += __shfl_xor(rsum[reg], 8);
    rsum[reg] = 1.0f / rsum[reg];
  }
#pragma unroll
  for (int ni = 0; ni < 4; ++ni) {
#pragma unroll
    for (int reg = 0; reg < 4; ++reg) {
      int row = w * 16 + l4 * 4 + reg;
      int a = l15 + 16 * ni;
      QH[row * 64 + ((((a >> 3) ^ (row & 7)) << 3)) + (a & 7)] =
          bf16rne(s[ni][reg] * rsum[reg]);
    }
  }
  __syncthreads();

  // ---- O = P @ agent_v (1 product) ----
  f32x4 o[4];
#pragma unroll
  for (int ni = 0; ni < 4; ++ni) o[ni] = (f32x4){0.f, 0.f, 0.f, 0.f};
#pragma unroll
  for (int ks = 0; ks < 2; ++ks) {
    int sw = (((ks << 2) + l4) ^ (l15 & 7)) << 3;
    s16x8 ph = *(const s16x8*)&QH[(w * 16 + l15) * 64 + sw];
#pragma unroll
    for (int ni = 0; ni < 4; ++ni) {
      s16x8 vh = *(const s16x8*)&AvH[(ni * 16 + l15) * 64 + sw];
      o[ni] = __builtin_amdgcn_mfma_f32_16x16x32_bf16(ph, vh, o[ni], 0, 0, 0);
    }
  }
  __syncthreads();  // all LDS dead -> olds / vlds may overwrite

  // ---- write O to LDS (stride 68) + stage v tile (bit-copy) ----
  float* olds = (float*)SMEM;                              // 17408B
  short* vlds = SMEM + 8704;                               // 9504B, disjoint
#pragma unroll
  for (int reg = 0; reg < 4; ++reg) {
    int row = w * 16 + l4 * 4 + reg;
#pragma unroll
    for (int ni = 0; ni < 4; ++ni)
      olds[row * 68 + l15 + 16 * ni] = o[ni][reg];
  }
  constexpr int VLD = 72;
  for (int idx = t; idx < 66 * 16; idx += 256) {
    int row = idx >> 4, cs = (idx & 15) << 2;
    int gr = i0 - 1 + row;
    s16x4 v = (s16x4)(short)0;
    if (gr >= 0 && gr < 4096)
      v = *(const s16x4*)&qkvb[((size_t)bg * Nn + gr) * LDQ + 2 * Cc + h * HD + cs];
    *(s16x4*)&vlds[row * VLD + cs] = v;
  }
  __syncthreads();

  // ---- re-gather: (local row, 8-ch chunk) -> one 16B store ----
#pragma unroll
  for (int it = 0; it < 2; ++it) {
    int widx = t + it * 256;            // 0..511
    int ml = widx >> 3, kc = widx & 7;
    int ig = i0 + ml;
    if (ig >= Nn) continue;
    float vals[8];
    *(float4*)&vals[0] = *(const float4*)&olds[ml * 68 + kc * 8];
    *(float4*)&vals[4] = *(const float4*)&olds[ml * 68 + kc * 8 + 4];
    if (ig < Nn - 1) {
      const int rl = ml + 1;
      const short* vr = &vlds[rl * VLD + kc * 8];
#pragma unroll
      for (int cI = 0; cI < 8; ++cI) {
        int cg = h * HD + kc * 8 + cI;
        float vm = bf2f(vr[cI - VLD]);
        float v0 = bf2f(vr[cI]);
        float vp = bf2f(vr[cI + VLD]);
        vals[cI] += dwcw[cg * 3] * vm + dwcw[cg * 3 + 1] * v0 +
                    dwcw[cg * 3 + 2] * vp + dwcb[cg];
      }
    }
    s16x8 hv;
#pragma unroll
    for (int cI = 0; cI < 8; ++cI) hv[cI] = bf16rne(vals[cI]);
    const int mrow = bg * Nn + ig;
    const int win = h * 64;
    const int jj = (kc ^ (mrow & 7)) * 8;
    *(s16x8*)&Opk[(size_t)mrow * KA + win + jj] = hv;
  }
}

}  // namespace

extern "C" void kernel_launch(void* const* d_in, const int* in_sizes, int n_in,
                              void* d_out, int out_size, void* d_ws,
                              size_t ws_size, hipStream_t stream) {
  const float* x = (const float*)d_in[0];
  const float* Wqkv = (const float*)d_in[1];
  const float* Wproj = (const float*)d_in[2];
  const float* bproj = (const float*)d_in[3];
  const float* dwcw = (const float*)d_in[4];
  const float* dwcb = (const float*)d_in[5];
  float* out = (float*)d_out;

  // --- fixed workspace: packed weight planes ---
  char* p = (char*)d_ws;
  short* WQpk = (short*)p; p += (size_t)LDQ * KP * 2;   // 7,077,888 B
  short* WPpk = (short*)p; p += (size_t)Cc * KP * 2;    // 2,359,296 B
  const size_t fixedBytes = (size_t)p - (size_t)d_ws;

  auto bytesFor = [&](int G) -> size_t {
    size_t Mg = (size_t)G * Nn;
    size_t Mpad = ((Mg + 127) / 128) * 128;
    size_t fl = (size_t)G * (Hh * NCH * Aa * 64 + Hh * NCH * Aa);  // paccv/s
    size_t sh = Mg * LDQ + (size_t)G * (Aa * Cc + Hh * Aa * HD) + Mpad * KA;
    return fixedBytes + fl * 4 + sh * 2;
  };
  int G = 1;
  for (int g = Bb; g >= 1; --g) {
    if (bytesFor(g) <= ws_size) { G = g; break; }
  }

  const size_t MgMax = (size_t)G * Nn;
  float* paccv = (float*)p;
  float* paccs = paccv + (size_t)G * Hh * NCH * Aa * 64;
  short* qkvb = (short*)(paccs + (size_t)G * Hh * NCH * Aa);
  short* atb = qkvb + MgMax * LDQ;
  short* avb = atb + (size_t)G * Aa * Cc;
  short* Apk = avb + (size_t)G * Hh * Aa * HD;   // aliased as Opk

  dim3 blk(256);
  // 0) pack weights (once per launch; deterministic)
  pack_w<<<dim3((96 * LDQ + 255) / 256), blk, 0, stream>>>(Wqkv, WQpk, LDQ);
  pack_w<<<dim3((96 * Cc + 255) / 256), blk, 0, stream>>>(Wproj, WPpk, Cc);

  for (int b0 = 0; b0 < Bb; b0 += G) {
    const int Gi = (b0 + G <= Bb) ? G : (Bb - b0);
    const int Mg = Gi * Nn;
    const int Mtiles = (Mg + 127) / 128;
    const float* xg = x + (size_t)b0 * Nn * Cc;
    float* outg = out + (size_t)b0 * Nn * Cc;

    // 1) pack x (RNE) -> Apk, then qkv (bf16) = x @ Wqkv
    pack_act<<<dim3((Mg * 96 + 255) / 256), blk, 0, stream>>>(xg, Apk, Mg);
    {
      const int nch = LDQ / 128;            // 18
      const int nwg = Mtiles * nch;
      gemm_pk2<true><<<dim3(nwg), blk, 0, stream>>>(Apk, WQpk, qkvb, nullptr,
                                                    Mg, LDQ, nch, nwg);
    }
    // 2) agent tokens (adaptive pool of bf16 q) -> atb (bf16)
    pool_agents<<<dim3(Gi * Aa), dim3(192), 0, stream>>>(qkvb, atb);
    // 3) agent attention partials (MFMA) + merge -> avb (bf16)
    agent_attn_mfma<<<dim3(NCH, Hh, Gi), blk, 0, stream>>>(qkvb, atb, paccv,
                                                           paccs);
    merge_agent<<<dim3(Gi * Hh), blk, 0, stream>>>(paccv, paccs, avb);
    // 4) fused q attention + dwc + pack (RNE) -> Opk(=Apk)
    q_attn_dwc<<<dim3((Nn + 63) / 64, Hh, Gi), blk, 0, stream>>>(
        qkvb, atb, avb, dwcw, dwcb, Apk);
    // 5) final projection (fp32 out, +bias)
    {
      const int nch = Cc / 128;             // 6
      const int nwg = Mtiles * nch;
      gemm_pk2<false><<<dim3(nwg), blk, 0, stream>>>(Apk, WPpk, outg, bproj,
                                                     Mg, Cc, nch, nwg);
    }
  }
}